// Round 1
// baseline (6221.426 us; speedup 1.0000x reference)
//
#include <hip/hip_runtime.h>
#include <hip/hip_bf16.h>
#include <cfloat>
#include <math.h>

#define SEQ    2048
#define HID    4096
#define NHEAD  32
#define NKVH   8
#define HDIM   128
#define QT     16
#define KTILE  64
#define HEAVY  204
#define RECENT 204
#define SELN   (SEQ - RECENT)   /* 1844 */
#define MCOLS  (SEQ + 1)        /* 2049 */

// ---------------- RoPE tables (match numpy fp32 pipeline) ----------------
__global__ void rope_tables_k(float* __restrict__ cost, float* __restrict__ sint) {
  int s = blockIdx.x, d = threadIdx.x;       // d in [0,128)
  int f = d & 63;
  float powv = (float)pow(10000.0, (double)f / 64.0);
  float invf = 1.0f / powv;                  // fp32 divide like np
  float ang  = (float)s * invf;              // fp32 multiply like np
  cost[s * HDIM + d] = (float)cos((double)ang);
  sint[s * HDIM + d] = (float)sin((double)ang);
}

// ---------------- RoPE apply, in place. x: [S][nheads*128] ----------------
__global__ void rope_apply_k(float* __restrict__ x, const float* __restrict__ cost,
                             const float* __restrict__ sint, int nheads) {
  int s = blockIdx.x, h = blockIdx.y, d = threadIdx.x;
  float* row = x + ((size_t)s * nheads + h) * HDIM;
  float v  = row[d];
  float vp = row[d ^ 64];
  __syncthreads();                           // all reads before any write
  float rot = (d < 64) ? -vp : vp;
  row[d] = v * cost[s * HDIM + d] + rot * sint[s * HDIM + d];
}

// ---------------- fp32 NT GEMM: C[m][n] = sum_k A[m][k]*B[n][k] + bias[n] ----
// 128x128 tile, BK=16, 256 threads, 8x8 microtile split 2x2 of 4x4.
__global__ __launch_bounds__(256) void gemm_nt_k(
    const float* __restrict__ A, const float* __restrict__ Bw,
    const float* __restrict__ bias, float* __restrict__ C,
    int M, int N, int K) {
  __shared__ __align__(16) float As[16][132];
  __shared__ __align__(16) float Bs[16][132];
  const int t = threadIdx.x;
  const int tx = t & 15, ty = t >> 4;
  const size_t bm = (size_t)blockIdx.y * 128, bn = (size_t)blockIdx.x * 128;
  const float* Ab = A + bm * K;
  const float* Bb = Bw + bn * K;
  float acc[2][2][4][4] = {};
  for (int k0 = 0; k0 < K; k0 += 16) {
    for (int i = t; i < 512; i += 256) {
      int m = i >> 2, kq = i & 3;
      float4 va = *(const float4*)(Ab + (size_t)m * K + k0 + kq * 4);
      As[kq*4+0][m] = va.x; As[kq*4+1][m] = va.y; As[kq*4+2][m] = va.z; As[kq*4+3][m] = va.w;
      float4 vb = *(const float4*)(Bb + (size_t)m * K + k0 + kq * 4);
      Bs[kq*4+0][m] = vb.x; Bs[kq*4+1][m] = vb.y; Bs[kq*4+2][m] = vb.z; Bs[kq*4+3][m] = vb.w;
    }
    __syncthreads();
#pragma unroll
    for (int kk = 0; kk < 16; ++kk) {
      float4 a0 = *(const float4*)&As[kk][ty * 4];
      float4 a1 = *(const float4*)&As[kk][64 + ty * 4];
      float4 b0 = *(const float4*)&Bs[kk][tx * 4];
      float4 b1 = *(const float4*)&Bs[kk][64 + tx * 4];
      float av[2][4] = {{a0.x,a0.y,a0.z,a0.w},{a1.x,a1.y,a1.z,a1.w}};
      float bv[2][4] = {{b0.x,b0.y,b0.z,b0.w},{b1.x,b1.y,b1.z,b1.w}};
#pragma unroll
      for (int ih = 0; ih < 2; ++ih)
#pragma unroll
        for (int i = 0; i < 4; ++i)
#pragma unroll
          for (int jh = 0; jh < 2; ++jh)
#pragma unroll
            for (int j = 0; j < 4; ++j)
              acc[ih][jh][i][j] = fmaf(av[ih][i], bv[jh][j], acc[ih][jh][i][j]);
    }
    __syncthreads();
  }
#pragma unroll
  for (int ih = 0; ih < 2; ++ih)
#pragma unroll
    for (int i = 0; i < 4; ++i) {
      size_t m = bm + ih * 64 + ty * 4 + i;
#pragma unroll
      for (int jh = 0; jh < 2; ++jh) {
        size_t n = bn + jh * 64 + tx * 4;
        float4 o;
        o.x = acc[ih][jh][i][0]; o.y = acc[ih][jh][i][1];
        o.z = acc[ih][jh][i][2]; o.w = acc[ih][jh][i][3];
        if (bias) { o.x += bias[n]; o.y += bias[n+1]; o.z += bias[n+2]; o.w += bias[n+3]; }
        *(float4*)(C + m * N + n) = o;
      }
    }
}

// ---------------- two-pass flash attention (fp32) ----------------
// grid (SEQ/QT, NHEAD), 256 threads.
// thread map (scores): c=t&15 (4 keys each), ds=(t>>4)&1 (d half), rg=t>>5 (rows rg, rg+8)
// thread map (PV/out): r2=t>>4 (row), dv=t&15 (8 dims)
__global__ __launch_bounds__(256) void attn_k(
    const float* __restrict__ qb, const float* __restrict__ kb, const float* __restrict__ vb,
    float* __restrict__ attn_out, float* __restrict__ cur_scores) {
  const int h = blockIdx.y;
  const int kh = h >> 2;              // GQA group of 4
  const int qbase = blockIdx.x * QT;
  const int t = threadIdx.x;
  const int c = t & 15;
  const int ds = (t >> 4) & 1;
  const int rg = t >> 5;
  const int row0 = qbase + rg, row1 = row0 + 8;

  __shared__ __align__(16) float q_s[QT][132];
  __shared__ __align__(16) float kv_s[KTILE][132];
  __shared__ float pT[KTILE][QT];
  __shared__ float cur_part[SEQ];

  for (int i = t; i < SEQ; i += 256) cur_part[i] = 0.0f;
  for (int i = t; i < QT * 32; i += 256) {
    int r = i >> 5, dq = i & 31;
    float4 v = *(const float4*)(qb + ((size_t)(qbase + r) * NHEAD + h) * HDIM + dq * 4);
    *(float4*)&q_s[r][dq * 4] = v;
  }

  const int ntiles = (qbase + QT + KTILE - 1) / KTILE;

  auto stage = [&](const float* __restrict__ src, int kt) {
    for (int i = t; i < KTILE * 32; i += 256) {
      int j = i >> 5, dq = i & 31;
      float4 v = *(const float4*)(src + ((size_t)(kt + j) * NKVH + kh) * HDIM + dq * 4);
      *(float4*)&kv_s[j][dq * 4] = v;
    }
  };
  auto compute_scores = [&](float (&sc)[2][4]) {
#pragma unroll
    for (int a = 0; a < 2; ++a)
#pragma unroll
      for (int jj = 0; jj < 4; ++jj) sc[a][jj] = 0.0f;
#pragma unroll 4
    for (int i = 0; i < 16; ++i) {
      const int di = (ds * 16 + i) * 4;
      const float4 q0 = *(const float4*)&q_s[rg][di];
      const float4 q1 = *(const float4*)&q_s[rg + 8][di];
#pragma unroll
      for (int jj = 0; jj < 4; ++jj) {
        const float4 k4 = *(const float4*)&kv_s[c * 4 + jj][di];
        sc[0][jj] = fmaf(q0.x, k4.x, sc[0][jj]);
        sc[0][jj] = fmaf(q0.y, k4.y, sc[0][jj]);
        sc[0][jj] = fmaf(q0.z, k4.z, sc[0][jj]);
        sc[0][jj] = fmaf(q0.w, k4.w, sc[0][jj]);
        sc[1][jj] = fmaf(q1.x, k4.x, sc[1][jj]);
        sc[1][jj] = fmaf(q1.y, k4.y, sc[1][jj]);
        sc[1][jj] = fmaf(q1.z, k4.z, sc[1][jj]);
        sc[1][jj] = fmaf(q1.w, k4.w, sc[1][jj]);
      }
    }
#pragma unroll
    for (int a = 0; a < 2; ++a)
#pragma unroll
      for (int jj = 0; jj < 4; ++jj) {
        float v = sc[a][jj];
        v += __shfl_xor(v, 16);            // d-split reduce
        sc[a][jj] = v / 11.313708498984761f;   // / sqrt(128), like ref
      }
  };

  float mrow[2] = {-FLT_MAX, -FLT_MAX};
  float lrow[2] = {0.0f, 0.0f};

  // -------- pass 1: row max + denominator (online) --------
  for (int tile = 0; tile < ntiles; ++tile) {
    const int kt = tile * KTILE;
    __syncthreads();
    stage(kb, kt);
    __syncthreads();
    float sc[2][4];
    compute_scores(sc);
#pragma unroll
    for (int a = 0; a < 2; ++a) {
      const int rowa = (a == 0) ? row0 : row1;
      float tmax = -FLT_MAX;
#pragma unroll
      for (int jj = 0; jj < 4; ++jj) {
        int j = kt + c * 4 + jj;
        if (j > rowa) sc[a][jj] = -FLT_MAX;
        tmax = fmaxf(tmax, sc[a][jj]);
      }
      for (int off = 1; off <= 8; off <<= 1) tmax = fmaxf(tmax, __shfl_xor(tmax, off));
      float mnew = fmaxf(mrow[a], tmax);
      float ts = 0.0f;
#pragma unroll
      for (int jj = 0; jj < 4; ++jj) ts += expf(sc[a][jj] - mnew); // masked -> exp(-huge)=0
      for (int off = 1; off <= 8; off <<= 1) ts += __shfl_xor(ts, off);
      lrow[a] = lrow[a] * expf(mrow[a] - mnew) + ts;
      mrow[a] = mnew;
    }
  }

  // -------- pass 2: probs -> cur_part, PV --------
  float o8[8] = {};
  const int r2 = t >> 4, dv = t & 15;
  for (int tile = 0; tile < ntiles; ++tile) {
    const int kt = tile * KTILE;
    __syncthreads();
    stage(kb, kt);
    __syncthreads();
    float sc[2][4];
    compute_scores(sc);
    float p[2][4];
#pragma unroll
    for (int a = 0; a < 2; ++a) {
      const int rowa = (a == 0) ? row0 : row1;
#pragma unroll
      for (int jj = 0; jj < 4; ++jj) {
        int j = kt + c * 4 + jj;
        p[a][jj] = (j <= rowa) ? (expf(sc[a][jj] - mrow[a]) / lrow[a]) : 0.0f;
      }
    }
    if (ds == 0) {
#pragma unroll
      for (int jj = 0; jj < 4; ++jj) {
        pT[c * 4 + jj][rg]     = p[0][jj];
        pT[c * 4 + jj][rg + 8] = p[1][jj];
        atomicAdd(&cur_part[kt + c * 4 + jj], p[0][jj] + p[1][jj]);
      }
    }
    __syncthreads();
    stage(vb, kt);
    __syncthreads();
#pragma unroll 8
    for (int jl = 0; jl < KTILE; ++jl) {
      float pp = pT[jl][r2];
      float4 v0 = *(const float4*)&kv_s[jl][dv * 8];
      float4 v1 = *(const float4*)&kv_s[jl][dv * 8 + 4];
      o8[0] = fmaf(pp, v0.x, o8[0]); o8[1] = fmaf(pp, v0.y, o8[1]);
      o8[2] = fmaf(pp, v0.z, o8[2]); o8[3] = fmaf(pp, v0.w, o8[3]);
      o8[4] = fmaf(pp, v1.x, o8[4]); o8[5] = fmaf(pp, v1.y, o8[5]);
      o8[6] = fmaf(pp, v1.z, o8[6]); o8[7] = fmaf(pp, v1.w, o8[7]);
    }
  }
  __syncthreads();

  {
    float* orow = attn_out + ((size_t)(qbase + r2) * NHEAD + h) * HDIM + dv * 8;
    float4 w0; w0.x = o8[0]; w0.y = o8[1]; w0.z = o8[2]; w0.w = o8[3];
    float4 w1; w1.x = o8[4]; w1.y = o8[5]; w1.z = o8[6]; w1.w = o8[7];
    *(float4*)orow = w0;
    *(float4*)(orow + 4) = w1;
  }
  const int kmax = qbase + QT;
  for (int i = t; i < kmax; i += 256)
    atomicAdd(&cur_scores[(size_t)h * SEQ + i], cur_part[i]);
}

// ---------------- heavy-hitter top-k -> mask row ----------------
__global__ __launch_bounds__(256) void topk_mask_k(const float* __restrict__ cur,
                                                   float* __restrict__ maskout) {
  const int hh = blockIdx.x;
  const int t = threadIdx.x;
  __shared__ float vals[SELN];
  __shared__ float wv[4];
  __shared__ int   wi[4];
  for (int ccol = t; ccol < MCOLS; ccol += 256)
    maskout[(size_t)hh * MCOLS + ccol] = (ccol >= MCOLS - RECENT) ? 1.0f : 0.0f;
  for (int i = t; i < SELN; i += 256) vals[i] = cur[(size_t)hh * SEQ + i];
  __syncthreads();
  for (int it = 0; it < HEAVY; ++it) {
    float bv = -INFINITY; int bi = 0x7fffffff;
    for (int i = t; i < SELN; i += 256) {
      float v = vals[i];
      if (v > bv) { bv = v; bi = i; }
    }
    for (int off = 1; off < 64; off <<= 1) {
      float ov = __shfl_xor(bv, off); int oi = __shfl_xor(bi, off);
      if (ov > bv || (ov == bv && oi < bi)) { bv = ov; bi = oi; }
    }
    int w = t >> 6;
    if ((t & 63) == 0) { wv[w] = bv; wi[w] = bi; }
    __syncthreads();
    if (t == 0) {
      float fbv = wv[0]; int fbi = wi[0];
      for (int k = 1; k < 4; ++k)
        if (wv[k] > fbv || (wv[k] == fbv && wi[k] < fbi)) { fbv = wv[k]; fbi = wi[k]; }
      maskout[(size_t)hh * MCOLS + fbi] = 1.0f;
      vals[fbi] = -INFINITY;
    }
    __syncthreads();
  }
}

extern "C" void kernel_launch(void* const* d_in, const int* in_sizes, int n_in,
                              void* d_out, int out_size, void* d_ws, size_t ws_size,
                              hipStream_t stream) {
  const float* hs = (const float*)d_in[0];
  const float* Wq = (const float*)d_in[1];
  const float* bq = (const float*)d_in[2];
  const float* Wk = (const float*)d_in[3];
  const float* bk = (const float*)d_in[4];
  const float* Wv = (const float*)d_in[5];
  const float* bv = (const float*)d_in[6];
  const float* Wo = (const float*)d_in[7];
  float* out = (float*)d_out;
  float* maskout = out + (size_t)SEQ * HID;

  float* ws   = (float*)d_ws;
  float* qbuf = ws;                                  // [S][NH*128]
  float* kbuf = qbuf + (size_t)SEQ * NHEAD * HDIM;   // [S][NKV*128]
  float* vbuf = kbuf + (size_t)SEQ * NKVH * HDIM;    // [S][NKV*128]
  float* aout = vbuf + (size_t)SEQ * NKVH * HDIM;    // [S][NH*128]
  float* cost = aout + (size_t)SEQ * NHEAD * HDIM;   // [S][128]
  float* sint = cost + (size_t)SEQ * HDIM;
  float* cur  = sint + (size_t)SEQ * HDIM;           // [NH][S]

  hipLaunchKernelGGL(rope_tables_k, dim3(SEQ), dim3(HDIM), 0, stream, cost, sint);

  hipLaunchKernelGGL(gemm_nt_k, dim3((NHEAD*HDIM)/128, SEQ/128), dim3(256), 0, stream,
                     hs, Wq, bq, qbuf, SEQ, NHEAD*HDIM, HID);
  hipLaunchKernelGGL(gemm_nt_k, dim3((NKVH*HDIM)/128, SEQ/128), dim3(256), 0, stream,
                     hs, Wk, bk, kbuf, SEQ, NKVH*HDIM, HID);
  hipLaunchKernelGGL(gemm_nt_k, dim3((NKVH*HDIM)/128, SEQ/128), dim3(256), 0, stream,
                     hs, Wv, bv, vbuf, SEQ, NKVH*HDIM, HID);

  hipLaunchKernelGGL(rope_apply_k, dim3(SEQ, NHEAD), dim3(HDIM), 0, stream, qbuf, cost, sint, NHEAD);
  hipLaunchKernelGGL(rope_apply_k, dim3(SEQ, NKVH), dim3(HDIM), 0, stream, kbuf, cost, sint, NKVH);

  hipMemsetAsync(cur, 0, (size_t)NHEAD * SEQ * sizeof(float), stream);

  hipLaunchKernelGGL(attn_k, dim3(SEQ/QT, NHEAD), dim3(256), 0, stream,
                     qbuf, kbuf, vbuf, aout, cur);

  hipLaunchKernelGGL(gemm_nt_k, dim3(HID/128, SEQ/128), dim3(256), 0, stream,
                     aout, Wo, (const float*)nullptr, out, SEQ, HID, HID);

  hipLaunchKernelGGL(topk_mask_k, dim3(NHEAD), dim3(256), 0, stream, cur, maskout);
}

// Round 2
// 2892.919 us; speedup vs baseline: 2.1506x; 2.1506x over previous
//
#include <hip/hip_runtime.h>
#include <hip/hip_bf16.h>
#include <cfloat>
#include <math.h>

#define SEQ    2048
#define HID    4096
#define NHEAD  32
#define NKVH   8
#define HDIM   128
#define QT     32
#define KTILE  64
#define HEAVY  204
#define RECENT 204
#define SELN   (SEQ - RECENT)   /* 1844 */
#define MCOLS  (SEQ + 1)        /* 2049 */

typedef unsigned short ushortT;
typedef unsigned int uintT;

// ---------------- helpers ----------------
__device__ __forceinline__ ushortT f2bf(float x) {
  uintT u = __float_as_uint(x);
  uintT r = (u + 0x7fffu + ((u >> 16) & 1u)) >> 16;   // RNE
  return (ushortT)r;
}
__device__ __forceinline__ float bf2f(ushortT h) {
  return __uint_as_float((uintT)h << 16);
}
__device__ __forceinline__ void gload16(const void* g, void* l) {
  __builtin_amdgcn_global_load_lds((const __attribute__((address_space(1))) void*)g,
                                   (__attribute__((address_space(3))) void*)l, 16, 0, 0);
}

// ---------------- RoPE tables (match numpy fp32 pipeline) ----------------
__global__ void rope_tables_k(float* __restrict__ cost, float* __restrict__ sint) {
  int s = blockIdx.x, d = threadIdx.x;
  int f = d & 63;
  float powv = (float)pow(10000.0, (double)f / 64.0);
  float invf = 1.0f / powv;
  float ang  = (float)s * invf;
  cost[s * HDIM + d] = (float)cos((double)ang);
  sint[s * HDIM + d] = (float)sin((double)ang);
}

// ---------------- RoPE apply, in place ----------------
__global__ void rope_apply_k(float* __restrict__ x, const float* __restrict__ cost,
                             const float* __restrict__ sint, int nheads) {
  int s = blockIdx.x, h = blockIdx.y, d = threadIdx.x;
  float* row = x + ((size_t)s * nheads + h) * HDIM;
  float v  = row[d];
  float vp = row[d ^ 64];
  __syncthreads();
  float rot = (d < 64) ? -vp : vp;
  row[d] = v * cost[s * HDIM + d] + rot * sint[s * HDIM + d];
}

// ---------------- fp32 -> bf16 hi/lo split conversion ----------------
__global__ void convert_split_k(const float* __restrict__ src, ushortT* __restrict__ hi,
                                ushortT* __restrict__ lo, int n4) {
  int i = blockIdx.x * blockDim.x + threadIdx.x;
  if (i >= n4) return;
  float4 v = ((const float4*)src)[i];
  ushort4 h, l;
  h.x = f2bf(v.x); l.x = f2bf(v.x - bf2f(h.x));
  h.y = f2bf(v.y); l.y = f2bf(v.y - bf2f(h.y));
  h.z = f2bf(v.z); l.z = f2bf(v.z - bf2f(h.z));
  h.w = f2bf(v.w); l.w = f2bf(v.w - bf2f(h.w));
  ((ushort4*)hi)[i] = h;
  ((ushort4*)lo)[i] = l;
}
__global__ void convert_hi_k(const float* __restrict__ src, ushortT* __restrict__ hi, int n4) {
  int i = blockIdx.x * blockDim.x + threadIdx.x;
  if (i >= n4) return;
  float4 v = ((const float4*)src)[i];
  ushort4 h;
  h.x = f2bf(v.x); h.y = f2bf(v.y); h.z = f2bf(v.z); h.w = f2bf(v.w);
  ((ushort4*)hi)[i] = h;
}

// ---------------- bf16 MFMA NT GEMM (split-precision capable) ----------------
// C[m][n] = sum_k A[m][k]*B[n][k] + bias[n].  NPROD=3: hi*hi + hi*lo + lo*hi.
template<int NPROD>
__global__ __launch_bounds__(256) void gemm_mfma_nt(
    const ushortT* __restrict__ Ahi, const ushortT* __restrict__ Alo,
    const ushortT* __restrict__ Bhi, const ushortT* __restrict__ Blo,
    const float* __restrict__ bias, float* __restrict__ C,
    int M, int N, int K) {
  using bf16x8 = __attribute__((ext_vector_type(8))) short;
  using f32x4  = __attribute__((ext_vector_type(4))) float;
  constexpr int NB = (NPROD == 3) ? 2 : 1;
  __shared__ __align__(16) ushortT As[NB][128 * 32];
  __shared__ __align__(16) ushortT Bs[NB][128 * 32];
  const int t = threadIdx.x;
  const int lane = t & 63, wid = t >> 6;
  const int wm = wid >> 1, wn = wid & 1;
  const size_t bm = (size_t)blockIdx.y * 128, bn = (size_t)blockIdx.x * 128;
  f32x4 acc[4][4] = {};
  const int r0 = t >> 2, kc0 = (t & 3) * 8;    // staging: 16B chunk per thread, x2

  for (int k0 = 0; k0 < K; k0 += 32) {
    __syncthreads();
    {
      const ushortT* ga = Ahi + (bm + r0) * (size_t)K + k0 + kc0;
      gload16(ga, &As[0][r0 * 32 + kc0]);
      gload16(ga + (size_t)64 * K, &As[0][(r0 + 64) * 32 + kc0]);
      const ushortT* gb = Bhi + (bn + r0) * (size_t)K + k0 + kc0;
      gload16(gb, &Bs[0][r0 * 32 + kc0]);
      gload16(gb + (size_t)64 * K, &Bs[0][(r0 + 64) * 32 + kc0]);
      if constexpr (NPROD == 3) {
        const ushortT* ga2 = Alo + (bm + r0) * (size_t)K + k0 + kc0;
        gload16(ga2, &As[1][r0 * 32 + kc0]);
        gload16(ga2 + (size_t)64 * K, &As[1][(r0 + 64) * 32 + kc0]);
        const ushortT* gb2 = Blo + (bn + r0) * (size_t)K + k0 + kc0;
        gload16(gb2, &Bs[1][r0 * 32 + kc0]);
        gload16(gb2 + (size_t)64 * K, &Bs[1][(r0 + 64) * 32 + kc0]);
      }
    }
    __syncthreads();
    const int frow = lane & 15, fk = (lane >> 4) * 8;
    bf16x8 ah[4], bh[4], al[4], bl[4];
#pragma unroll
    for (int f = 0; f < 4; ++f) {
      ah[f] = *(const bf16x8*)&As[0][(wm * 64 + f * 16 + frow) * 32 + fk];
      bh[f] = *(const bf16x8*)&Bs[0][(wn * 64 + f * 16 + frow) * 32 + fk];
      if constexpr (NPROD == 3) {
        al[f] = *(const bf16x8*)&As[1][(wm * 64 + f * 16 + frow) * 32 + fk];
        bl[f] = *(const bf16x8*)&Bs[1][(wn * 64 + f * 16 + frow) * 32 + fk];
      }
    }
#pragma unroll
    for (int fr = 0; fr < 4; ++fr)
#pragma unroll
      for (int fc = 0; fc < 4; ++fc) {
        acc[fr][fc] = __builtin_amdgcn_mfma_f32_16x16x32_bf16(ah[fr], bh[fc], acc[fr][fc], 0, 0, 0);
        if constexpr (NPROD == 3) {
          acc[fr][fc] = __builtin_amdgcn_mfma_f32_16x16x32_bf16(ah[fr], bl[fc], acc[fr][fc], 0, 0, 0);
          acc[fr][fc] = __builtin_amdgcn_mfma_f32_16x16x32_bf16(al[fr], bh[fc], acc[fr][fc], 0, 0, 0);
        }
      }
  }
  // epilogue: D layout col=lane&15, row=(lane>>4)*4+reg
  const int crow = (lane >> 4) * 4, ccol = lane & 15;
#pragma unroll
  for (int fr = 0; fr < 4; ++fr)
#pragma unroll
    for (int fc = 0; fc < 4; ++fc) {
      size_t col = bn + wn * 64 + fc * 16 + ccol;
      float badd = bias ? bias[col] : 0.0f;
#pragma unroll
      for (int i = 0; i < 4; ++i) {
        size_t row = bm + wm * 64 + fr * 16 + crow + i;
        C[row * (size_t)N + col] = acc[fr][fc][i] + badd;
      }
    }
}

// ---------------- two-pass flash attention (fp32 scores, QT=32) ----------------
// grid (SEQ/QT, NHEAD), 256 threads.
// score map: c=t&15 (keys c*4..+3), ds=(t>>4)&1 (d-half), rg=t>>5 (rows rg+8a, a=0..3)
// PV map:    r2=t>>4 (rows r2, r2+16), dv=t&15 (floats dv*8..+7)
__global__ __launch_bounds__(256) void attn_k(
    const float* __restrict__ qb, const float* __restrict__ kb, const float* __restrict__ vb,
    float* __restrict__ attn_out, float* __restrict__ cur_scores) {
  const int h = blockIdx.y;
  const int kh = h >> 2;
  const int qbase = ((int)gridDim.x - 1 - (int)blockIdx.x) * QT;  // big work first
  const int t = threadIdx.x;
  const int c = t & 15, ds = (t >> 4) & 1, rg = t >> 5;

  __shared__ __align__(16) float q_s[QT][128];      // XOR chunk-swizzled
  __shared__ __align__(16) float kv_s[KTILE][128];  // XOR chunk-swizzled
  __shared__ __hip_bfloat16 pT[KTILE][QT + 1];
  __shared__ float cur_part[KTILE];

  if (t < KTILE) cur_part[t] = 0.0f;
  for (int i = t; i < QT * 32; i += 256) {
    int r = i >> 5, ch = i & 31;
    float4 v = *(const float4*)(qb + ((size_t)(qbase + r) * NHEAD + h) * HDIM + ch * 4);
    *(float4*)&q_s[r][(ch ^ ((r >> 2) & 7)) * 4] = v;
  }

  const int ntiles = (qbase + QT + KTILE - 1) / KTILE;

  auto stage = [&](const float* __restrict__ src, int kt) {
    for (int i = t; i < KTILE * 32; i += 256) {
      int r = i >> 5, ch = i & 31;
      float4 v = *(const float4*)(src + ((size_t)(kt + r) * NKVH + kh) * HDIM + ch * 4);
      *(float4*)&kv_s[r][(ch ^ ((r >> 2) & 7)) * 4] = v;
    }
  };

  auto compute_scores = [&](float (&sc)[4][4]) {
#pragma unroll
    for (int a = 0; a < 4; ++a)
#pragma unroll
      for (int jj = 0; jj < 4; ++jj) sc[a][jj] = 0.0f;
#pragma unroll 4
    for (int i = 0; i < 16; ++i) {
      const int ch = ds * 16 + i;
      float4 qv[4], kv4[4];
#pragma unroll
      for (int a = 0; a < 4; ++a) {
        int qr = rg + 8 * a;
        qv[a] = *(const float4*)&q_s[qr][(ch ^ ((qr >> 2) & 7)) * 4];
      }
#pragma unroll
      for (int jj = 0; jj < 4; ++jj) {
        int kr = c * 4 + jj;
        kv4[jj] = *(const float4*)&kv_s[kr][(ch ^ ((kr >> 2) & 7)) * 4];
      }
#pragma unroll
      for (int a = 0; a < 4; ++a)
#pragma unroll
        for (int jj = 0; jj < 4; ++jj) {
          sc[a][jj] = fmaf(qv[a].x, kv4[jj].x, sc[a][jj]);
          sc[a][jj] = fmaf(qv[a].y, kv4[jj].y, sc[a][jj]);
          sc[a][jj] = fmaf(qv[a].z, kv4[jj].z, sc[a][jj]);
          sc[a][jj] = fmaf(qv[a].w, kv4[jj].w, sc[a][jj]);
        }
    }
#pragma unroll
    for (int a = 0; a < 4; ++a)
#pragma unroll
      for (int jj = 0; jj < 4; ++jj) {
        float v = sc[a][jj];
        v += __shfl_xor(v, 16);
        sc[a][jj] = v / 11.313708498984761f;
      }
  };

  float m4[4], l4[4];
#pragma unroll
  for (int a = 0; a < 4; ++a) { m4[a] = -FLT_MAX; l4[a] = 0.0f; }

  // -------- pass 1: row max + denominator --------
  for (int tile = 0; tile < ntiles; ++tile) {
    const int kt = tile * KTILE;
    __syncthreads();
    stage(kb, kt);
    __syncthreads();
    float sc[4][4];
    compute_scores(sc);
#pragma unroll
    for (int a = 0; a < 4; ++a) {
      const int row = qbase + rg + 8 * a;
      float tmax = -FLT_MAX;
#pragma unroll
      for (int jj = 0; jj < 4; ++jj) {
        int j = kt + c * 4 + jj;
        if (j > row) sc[a][jj] = -FLT_MAX;
        tmax = fmaxf(tmax, sc[a][jj]);
      }
      for (int off = 1; off <= 8; off <<= 1) tmax = fmaxf(tmax, __shfl_xor(tmax, off));
      float mnew = fmaxf(m4[a], tmax);
      float ts = 0.0f;
#pragma unroll
      for (int jj = 0; jj < 4; ++jj) ts += expf(sc[a][jj] - mnew);
      for (int off = 1; off <= 8; off <<= 1) ts += __shfl_xor(ts, off);
      l4[a] = l4[a] * expf(m4[a] - mnew) + ts;
      m4[a] = mnew;
    }
  }

  // -------- pass 2: probs -> pT (bf16) + cur_part, PV --------
  float o[2][8] = {};
  const int r2 = t >> 4, dv = t & 15;
  for (int tile = 0; tile < ntiles; ++tile) {
    const int kt = tile * KTILE;
    __syncthreads();
    stage(kb, kt);
    __syncthreads();
    float sc[4][4];
    compute_scores(sc);
    float pj[4][4];
#pragma unroll
    for (int a = 0; a < 4; ++a) {
      const int row = qbase + rg + 8 * a;
#pragma unroll
      for (int jj = 0; jj < 4; ++jj) {
        int j = kt + c * 4 + jj;
        float p = (j <= row) ? (expf(sc[a][jj] - m4[a]) / l4[a]) : 0.0f;
        pj[a][jj] = p;
        if (ds == 0) pT[c * 4 + jj][rg + 8 * a] = __float2bfloat16(p);
      }
    }
    if (ds == 0) {
#pragma unroll
      for (int jj = 0; jj < 4; ++jj)
        atomicAdd(&cur_part[c * 4 + jj], pj[0][jj] + pj[1][jj] + pj[2][jj] + pj[3][jj]);
    }
    __syncthreads();                     // pT/cur done; K reads done
    stage(vb, kt);
    if (t < KTILE) {
      atomicAdd(&cur_scores[(size_t)h * SEQ + kt + t], cur_part[t]);
      cur_part[t] = 0.0f;
    }
    __syncthreads();                     // V staged, cur flushed+reset
#pragma unroll 4
    for (int jl = 0; jl < KTILE; ++jl) {
      float pa = __bfloat162float(pT[jl][r2]);
      float pb = __bfloat162float(pT[jl][r2 + 16]);
      int sw = (jl >> 2) & 7;
      float4 v0 = *(const float4*)&kv_s[jl][((dv * 2) ^ sw) * 4];
      float4 v1 = *(const float4*)&kv_s[jl][((dv * 2 + 1) ^ sw) * 4];
      o[0][0] = fmaf(pa, v0.x, o[0][0]); o[0][1] = fmaf(pa, v0.y, o[0][1]);
      o[0][2] = fmaf(pa, v0.z, o[0][2]); o[0][3] = fmaf(pa, v0.w, o[0][3]);
      o[0][4] = fmaf(pa, v1.x, o[0][4]); o[0][5] = fmaf(pa, v1.y, o[0][5]);
      o[0][6] = fmaf(pa, v1.z, o[0][6]); o[0][7] = fmaf(pa, v1.w, o[0][7]);
      o[1][0] = fmaf(pb, v0.x, o[1][0]); o[1][1] = fmaf(pb, v0.y, o[1][1]);
      o[1][2] = fmaf(pb, v0.z, o[1][2]); o[1][3] = fmaf(pb, v0.w, o[1][3]);
      o[1][4] = fmaf(pb, v1.x, o[1][4]); o[1][5] = fmaf(pb, v1.y, o[1][5]);
      o[1][6] = fmaf(pb, v1.z, o[1][6]); o[1][7] = fmaf(pb, v1.w, o[1][7]);
    }
  }

  {
    float* orow = attn_out + ((size_t)(qbase + r2) * NHEAD + h) * HDIM + dv * 8;
    float4 w0, w1;
    w0.x = o[0][0]; w0.y = o[0][1]; w0.z = o[0][2]; w0.w = o[0][3];
    w1.x = o[0][4]; w1.y = o[0][5]; w1.z = o[0][6]; w1.w = o[0][7];
    *(float4*)orow = w0; *(float4*)(orow + 4) = w1;
    float* orow2 = attn_out + ((size_t)(qbase + r2 + 16) * NHEAD + h) * HDIM + dv * 8;
    w0.x = o[1][0]; w0.y = o[1][1]; w0.z = o[1][2]; w0.w = o[1][3];
    w1.x = o[1][4]; w1.y = o[1][5]; w1.z = o[1][6]; w1.w = o[1][7];
    *(float4*)orow2 = w0; *(float4*)(orow2 + 4) = w1;
  }
}

// ---------------- heavy-hitter top-k -> mask row ----------------
__global__ __launch_bounds__(256) void topk_mask_k(const float* __restrict__ cur,
                                                   float* __restrict__ maskout) {
  const int hh = blockIdx.x;
  const int t = threadIdx.x;
  __shared__ float vals[SELN];
  __shared__ float wv[4];
  __shared__ int   wi[4];
  for (int ccol = t; ccol < MCOLS; ccol += 256)
    maskout[(size_t)hh * MCOLS + ccol] = (ccol >= MCOLS - RECENT) ? 1.0f : 0.0f;
  for (int i = t; i < SELN; i += 256) vals[i] = cur[(size_t)hh * SEQ + i];
  __syncthreads();
  for (int it = 0; it < HEAVY; ++it) {
    float bv = -INFINITY; int bi = 0x7fffffff;
    for (int i = t; i < SELN; i += 256) {
      float v = vals[i];
      if (v > bv) { bv = v; bi = i; }
    }
    for (int off = 1; off < 64; off <<= 1) {
      float ov = __shfl_xor(bv, off); int oi = __shfl_xor(bi, off);
      if (ov > bv || (ov == bv && oi < bi)) { bv = ov; bi = oi; }
    }
    int w = t >> 6;
    if ((t & 63) == 0) { wv[w] = bv; wi[w] = bi; }
    __syncthreads();
    if (t == 0) {
      float fbv = wv[0]; int fbi = wi[0];
      for (int k = 1; k < 4; ++k)
        if (wv[k] > fbv || (wv[k] == fbv && wi[k] < fbi)) { fbv = wv[k]; fbi = wi[k]; }
      maskout[(size_t)hh * MCOLS + fbi] = 1.0f;
      vals[fbi] = -INFINITY;
    }
    __syncthreads();
  }
}

extern "C" void kernel_launch(void* const* d_in, const int* in_sizes, int n_in,
                              void* d_out, int out_size, void* d_ws, size_t ws_size,
                              hipStream_t stream) {
  const float* hs = (const float*)d_in[0];
  const float* Wq = (const float*)d_in[1];
  const float* bq = (const float*)d_in[2];
  const float* Wk = (const float*)d_in[3];
  const float* bk = (const float*)d_in[4];
  const float* Wv = (const float*)d_in[5];
  const float* bv = (const float*)d_in[6];
  const float* Wo = (const float*)d_in[7];
  float* out = (float*)d_out;
  float* maskout = out + (size_t)SEQ * HID;

  char* w = (char*)d_ws;
  auto alloc = [&](size_t bytes) { char* p = w; w += (bytes + 255) & ~(size_t)255; return p; };
  float*   qbuf   = (float*)alloc((size_t)SEQ * NHEAD * HDIM * 4);
  float*   kbuf   = (float*)alloc((size_t)SEQ * NKVH * HDIM * 4);
  float*   vbuf   = (float*)alloc((size_t)SEQ * NKVH * HDIM * 4);
  float*   aout   = (float*)alloc((size_t)SEQ * NHEAD * HDIM * 4);
  float*   cost   = (float*)alloc((size_t)SEQ * HDIM * 4);
  float*   sint   = (float*)alloc((size_t)SEQ * HDIM * 4);
  float*   cur    = (float*)alloc((size_t)NHEAD * SEQ * 4);
  ushortT* hshi   = (ushortT*)alloc((size_t)SEQ * HID * 2);
  ushortT* hslo   = (ushortT*)alloc((size_t)SEQ * HID * 2);
  ushortT* wqhi   = (ushortT*)alloc((size_t)HID * HID * 2);
  ushortT* wqlo   = (ushortT*)alloc((size_t)HID * HID * 2);
  ushortT* wkhi   = (ushortT*)alloc((size_t)NKVH * HDIM * HID * 2);
  ushortT* wklo   = (ushortT*)alloc((size_t)NKVH * HDIM * HID * 2);
  ushortT* wvhi   = (ushortT*)alloc((size_t)NKVH * HDIM * HID * 2);
  ushortT* wohi   = (ushortT*)alloc((size_t)HID * HID * 2);
  ushortT* aouthi = (ushortT*)alloc((size_t)SEQ * HID * 2);

  hipLaunchKernelGGL(rope_tables_k, dim3(SEQ), dim3(HDIM), 0, stream, cost, sint);

  // conversions
  {
    int n4;
    n4 = SEQ * HID / 4;
    hipLaunchKernelGGL(convert_split_k, dim3((n4 + 255) / 256), dim3(256), 0, stream, hs, hshi, hslo, n4);
    n4 = HID * HID / 4;
    hipLaunchKernelGGL(convert_split_k, dim3((n4 + 255) / 256), dim3(256), 0, stream, Wq, wqhi, wqlo, n4);
    n4 = NKVH * HDIM * HID / 4;
    hipLaunchKernelGGL(convert_split_k, dim3((n4 + 255) / 256), dim3(256), 0, stream, Wk, wkhi, wklo, n4);
    hipLaunchKernelGGL(convert_hi_k, dim3((n4 + 255) / 256), dim3(256), 0, stream, Wv, wvhi, n4);
    n4 = HID * HID / 4;
    hipLaunchKernelGGL(convert_hi_k, dim3((n4 + 255) / 256), dim3(256), 0, stream, Wo, wohi, n4);
  }

  // projections (MFMA)
  hipLaunchKernelGGL((gemm_mfma_nt<3>), dim3((NHEAD * HDIM) / 128, SEQ / 128), dim3(256), 0, stream,
                     hshi, hslo, wqhi, wqlo, bq, qbuf, SEQ, NHEAD * HDIM, HID);
  hipLaunchKernelGGL((gemm_mfma_nt<3>), dim3((NKVH * HDIM) / 128, SEQ / 128), dim3(256), 0, stream,
                     hshi, hslo, wkhi, wklo, bk, kbuf, SEQ, NKVH * HDIM, HID);
  hipLaunchKernelGGL((gemm_mfma_nt<1>), dim3((NKVH * HDIM) / 128, SEQ / 128), dim3(256), 0, stream,
                     hshi, (const ushortT*)nullptr, wvhi, (const ushortT*)nullptr, bv, vbuf,
                     SEQ, NKVH * HDIM, HID);

  hipLaunchKernelGGL(rope_apply_k, dim3(SEQ, NHEAD), dim3(HDIM), 0, stream, qbuf, cost, sint, NHEAD);
  hipLaunchKernelGGL(rope_apply_k, dim3(SEQ, NKVH), dim3(HDIM), 0, stream, kbuf, cost, sint, NKVH);

  hipMemsetAsync(cur, 0, (size_t)NHEAD * SEQ * sizeof(float), stream);

  hipLaunchKernelGGL(attn_k, dim3(SEQ / QT, NHEAD), dim3(256), 0, stream,
                     qbuf, kbuf, vbuf, aout, cur);

  // out projection (plain bf16 MFMA)
  {
    int n4 = SEQ * HID / 4;
    hipLaunchKernelGGL(convert_hi_k, dim3((n4 + 255) / 256), dim3(256), 0, stream, aout, aouthi, n4);
  }
  hipLaunchKernelGGL((gemm_mfma_nt<1>), dim3(HID / 128, SEQ / 128), dim3(256), 0, stream,
                     aouthi, (const ushortT*)nullptr, wohi, (const ushortT*)nullptr,
                     (const float*)nullptr, out, SEQ, HID, HID);

  hipLaunchKernelGGL(topk_mask_k, dim3(NHEAD), dim3(256), 0, stream, cur, maskout);
}

// Round 3
// 1268.015 us; speedup vs baseline: 4.9064x; 2.2815x over previous
//
#include <hip/hip_runtime.h>
#include <hip/hip_bf16.h>
#include <cfloat>
#include <math.h>

#define SEQ    2048
#define HID    4096
#define NHEAD  32
#define NKVH   8
#define HDIM   128
#define HEAVY  204
#define RECENT 204
#define SELN   (SEQ - RECENT)   /* 1844 */
#define MCOLS  (SEQ + 1)        /* 2049 */

typedef unsigned short ushortT;
typedef unsigned int uintT;

using bf16x8 = __attribute__((ext_vector_type(8))) short;
using f32x4  = __attribute__((ext_vector_type(4))) float;

// ---------------- helpers ----------------
__device__ __forceinline__ ushortT f2bf(float x) {
  uintT u = __float_as_uint(x);
  uintT r = (u + 0x7fffu + ((u >> 16) & 1u)) >> 16;   // RNE
  return (ushortT)r;
}
__device__ __forceinline__ float bf2f(ushortT h) {
  return __uint_as_float((uintT)h << 16);
}
__device__ __forceinline__ void gload16(const void* g, void* l) {
  __builtin_amdgcn_global_load_lds((const __attribute__((address_space(1))) void*)g,
                                   (__attribute__((address_space(3))) void*)l, 16, 0, 0);
}

// ---------------- RoPE tables (match numpy fp32 pipeline) ----------------
__global__ void rope_tables_k(float* __restrict__ cost, float* __restrict__ sint) {
  int s = blockIdx.x, d = threadIdx.x;
  int f = d & 63;
  float powv = (float)pow(10000.0, (double)f / 64.0);
  float invf = 1.0f / powv;
  float ang  = (float)s * invf;
  cost[s * HDIM + d] = (float)cos((double)ang);
  sint[s * HDIM + d] = (float)sin((double)ang);
}

// ---------------- RoPE apply, in place ----------------
__global__ void rope_apply_k(float* __restrict__ x, const float* __restrict__ cost,
                             const float* __restrict__ sint, int nheads) {
  int s = blockIdx.x, h = blockIdx.y, d = threadIdx.x;
  float* row = x + ((size_t)s * nheads + h) * HDIM;
  float v  = row[d];
  float vp = row[d ^ 64];
  __syncthreads();
  float rot = (d < 64) ? -vp : vp;
  row[d] = v * cost[s * HDIM + d] + rot * sint[s * HDIM + d];
}

// ---------------- fp32 -> bf16 hi/lo split conversion ----------------
__global__ void convert_split_k(const float* __restrict__ src, ushortT* __restrict__ hi,
                                ushortT* __restrict__ lo, int n4) {
  int i = blockIdx.x * blockDim.x + threadIdx.x;
  if (i >= n4) return;
  float4 v = ((const float4*)src)[i];
  ushort4 h, l;
  h.x = f2bf(v.x); l.x = f2bf(v.x - bf2f(h.x));
  h.y = f2bf(v.y); l.y = f2bf(v.y - bf2f(h.y));
  h.z = f2bf(v.z); l.z = f2bf(v.z - bf2f(h.z));
  h.w = f2bf(v.w); l.w = f2bf(v.w - bf2f(h.w));
  ((ushort4*)hi)[i] = h;
  ((ushort4*)lo)[i] = l;
}
__global__ void convert_hi_k(const float* __restrict__ src, ushortT* __restrict__ hi, int n4) {
  int i = blockIdx.x * blockDim.x + threadIdx.x;
  if (i >= n4) return;
  float4 v = ((const float4*)src)[i];
  ushort4 h;
  h.x = f2bf(v.x); h.y = f2bf(v.y); h.z = f2bf(v.z); h.w = f2bf(v.w);
  ((ushort4*)hi)[i] = h;
}
// K: pre-scale by 1/sqrt(128), then split hi/lo
__global__ void convert_khl_k(const float* __restrict__ src, ushortT* __restrict__ hi,
                              ushortT* __restrict__ lo, int n4) {
  int i = blockIdx.x * blockDim.x + threadIdx.x;
  if (i >= n4) return;
  const float s = 0.08838834764831845f;
  float4 v = ((const float4*)src)[i];
  v.x *= s; v.y *= s; v.z *= s; v.w *= s;
  ushort4 h, l;
  h.x = f2bf(v.x); l.x = f2bf(v.x - bf2f(h.x));
  h.y = f2bf(v.y); l.y = f2bf(v.y - bf2f(h.y));
  h.z = f2bf(v.z); l.z = f2bf(v.z - bf2f(h.z));
  h.w = f2bf(v.w); l.w = f2bf(v.w - bf2f(h.w));
  ((ushort4*)hi)[i] = h;
  ((ushort4*)lo)[i] = l;
}

// ---------------- V transpose: vbuf [S][NKVH][128] fp32 -> vt [NKVH][128][S] bf16 --------
__global__ __launch_bounds__(256) void transpose_v_k(const float* __restrict__ vbuf,
                                                     ushortT* __restrict__ vt) {
  int g = blockIdx.x * 256 + threadIdx.x;
  int d = g & 127;
  int rest = g >> 7;
  int sblk = rest & (SEQ / 8 - 1);
  int kh = rest >> 8;
  ushortT tmp[8];
#pragma unroll
  for (int i = 0; i < 8; ++i) {
    float v = vbuf[((size_t)(sblk * 8 + i) * NKVH + kh) * HDIM + d];
    tmp[i] = f2bf(v);
  }
  ushortT* o = vt + ((size_t)kh * HDIM + d) * SEQ + sblk * 8;
  *(ushort4*)o = *(ushort4*)tmp;
  *(ushort4*)(o + 4) = *(ushort4*)&tmp[4];
}

// ---------------- bf16 MFMA NT GEMM (split-precision capable) ----------------
template<int NPROD>
__global__ __launch_bounds__(256) void gemm_mfma_nt(
    const ushortT* __restrict__ Ahi, const ushortT* __restrict__ Alo,
    const ushortT* __restrict__ Bhi, const ushortT* __restrict__ Blo,
    const float* __restrict__ bias, float* __restrict__ C,
    int M, int N, int K) {
  constexpr int NB = (NPROD == 3) ? 2 : 1;
  __shared__ __align__(16) ushortT As[NB][128 * 32];
  __shared__ __align__(16) ushortT Bs[NB][128 * 32];
  const int t = threadIdx.x;
  const int lane = t & 63, wid = t >> 6;
  const int wm = wid >> 1, wn = wid & 1;
  const size_t bm = (size_t)blockIdx.y * 128, bn = (size_t)blockIdx.x * 128;
  f32x4 acc[4][4] = {};
  const int r0 = t >> 2, kc0 = (t & 3) * 8;

  for (int k0 = 0; k0 < K; k0 += 32) {
    __syncthreads();
    {
      const ushortT* ga = Ahi + (bm + r0) * (size_t)K + k0 + kc0;
      gload16(ga, &As[0][r0 * 32 + kc0]);
      gload16(ga + (size_t)64 * K, &As[0][(r0 + 64) * 32 + kc0]);
      const ushortT* gb = Bhi + (bn + r0) * (size_t)K + k0 + kc0;
      gload16(gb, &Bs[0][r0 * 32 + kc0]);
      gload16(gb + (size_t)64 * K, &Bs[0][(r0 + 64) * 32 + kc0]);
      if constexpr (NPROD == 3) {
        const ushortT* ga2 = Alo + (bm + r0) * (size_t)K + k0 + kc0;
        gload16(ga2, &As[1][r0 * 32 + kc0]);
        gload16(ga2 + (size_t)64 * K, &As[1][(r0 + 64) * 32 + kc0]);
        const ushortT* gb2 = Blo + (bn + r0) * (size_t)K + k0 + kc0;
        gload16(gb2, &Bs[1][r0 * 32 + kc0]);
        gload16(gb2 + (size_t)64 * K, &Bs[1][(r0 + 64) * 32 + kc0]);
      }
    }
    __syncthreads();
    const int frow = lane & 15, fk = (lane >> 4) * 8;
    bf16x8 ah[4], bh[4], al[4], bl[4];
#pragma unroll
    for (int f = 0; f < 4; ++f) {
      ah[f] = *(const bf16x8*)&As[0][(wm * 64 + f * 16 + frow) * 32 + fk];
      bh[f] = *(const bf16x8*)&Bs[0][(wn * 64 + f * 16 + frow) * 32 + fk];
      if constexpr (NPROD == 3) {
        al[f] = *(const bf16x8*)&As[1][(wm * 64 + f * 16 + frow) * 32 + fk];
        bl[f] = *(const bf16x8*)&Bs[1][(wn * 64 + f * 16 + frow) * 32 + fk];
      }
    }
#pragma unroll
    for (int fr = 0; fr < 4; ++fr)
#pragma unroll
      for (int fc = 0; fc < 4; ++fc) {
        acc[fr][fc] = __builtin_amdgcn_mfma_f32_16x16x32_bf16(ah[fr], bh[fc], acc[fr][fc], 0, 0, 0);
        if constexpr (NPROD == 3) {
          acc[fr][fc] = __builtin_amdgcn_mfma_f32_16x16x32_bf16(ah[fr], bl[fc], acc[fr][fc], 0, 0, 0);
          acc[fr][fc] = __builtin_amdgcn_mfma_f32_16x16x32_bf16(al[fr], bh[fc], acc[fr][fc], 0, 0, 0);
        }
      }
  }
  const int crow = (lane >> 4) * 4, ccol = lane & 15;
#pragma unroll
  for (int fr = 0; fr < 4; ++fr)
#pragma unroll
    for (int fc = 0; fc < 4; ++fc) {
      size_t col = bn + wn * 64 + fc * 16 + ccol;
      float badd = bias ? bias[col] : 0.0f;
#pragma unroll
      for (int i = 0; i < 4; ++i) {
        size_t row = bm + wm * 64 + fr * 16 + crow + i;
        C[row * (size_t)N + col] = acc[fr][fc][i] + badd;
      }
    }
}

// ---------------- MFMA flash attention, two-pass, swapped (S^T = K·Q) ----------------
// grid (SEQ/64, NHEAD), 256 thr = 4 waves; wave owns 16 q-columns.
// K pre-scaled by 1/sqrt(128) and split hi/lo (3-product fp32-grade scores).
__global__ __launch_bounds__(256, 2) void attn_mfma_k(
    const float* __restrict__ qb, const ushortT* __restrict__ khi,
    const ushortT* __restrict__ klo, const ushortT* __restrict__ vt,
    ushortT* __restrict__ aout_bf, float* __restrict__ cur_scores) {
  const int h = blockIdx.y, kh = h >> 2;
  const int qb0 = ((int)gridDim.x - 1 - (int)blockIdx.x) * 64;   // big work first
  const int t = threadIdx.x, lane = t & 63, wid = t >> 6;
  const int lq = lane & 15, lg = lane >> 4;
  const int qrow = qb0 + wid * 16 + lq;

  __shared__ __align__(16) ushortT Khi_s[64 * 128];   // chunk-swizzled: c' = c ^ (k&7)
  __shared__ __align__(16) ushortT Klo_s[64 * 128];
  __shared__ __align__(16) ushortT VT_s[128 * 64];    // c' = c ^ (d&7)
  __shared__ ushortT pT_s[4][64][18];                 // per-wave P^T [k][q], pad 18

  // ---- Q fragments (hi/lo) in registers; B-operand: col=q=lq, k-elems d=ds*32+lg*8..+7
  bf16x8 qh[4], ql[4];
#pragma unroll
  for (int ds = 0; ds < 4; ++ds) {
    const float* qp = qb + (size_t)qrow * (NHEAD * HDIM) + h * HDIM + ds * 32 + lg * 8;
    float4 a = *(const float4*)qp, b = *(const float4*)(qp + 4);
    float v[8] = {a.x, a.y, a.z, a.w, b.x, b.y, b.z, b.w};
#pragma unroll
    for (int j = 0; j < 8; ++j) {
      ushortT hh = f2bf(v[j]);
      qh[ds][j] = (short)hh;
      ql[ds][j] = (short)f2bf(v[j] - bf2f(hh));
    }
  }

  const int ntiles = qb0 / 64 + 1;
  float m = -1e30f, l = 0.0f;

  // ================= PASS 1: row max + denominator =================
  for (int tile = 0; tile < ntiles; ++tile) {
    const int kt = tile * 64;
    __syncthreads();
#pragma unroll
    for (int r = 0; r < 4; ++r) {          // stage K hi/lo (pre-swizzled source)
      int cid = r * 256 + t;
      int k = cid >> 4, cp = cid & 15, c = cp ^ (k & 7);
      size_t goff = ((size_t)(kt + k) * NKVH + kh) * HDIM + c * 8;
      gload16(khi + goff, &Khi_s[cid * 8]);
      gload16(klo + goff, &Klo_s[cid * 8]);
    }
    __syncthreads();
    f32x4 acc[4] = {};
#pragma unroll
    for (int ds = 0; ds < 4; ++ds)
#pragma unroll
      for (int kf = 0; kf < 4; ++kf) {
        int krow = kf * 16 + lq;
        int cp = (ds * 4 + lg) ^ (krow & 7);
        bf16x8 ah = *(const bf16x8*)&Khi_s[krow * 128 + cp * 8];
        bf16x8 al = *(const bf16x8*)&Klo_s[krow * 128 + cp * 8];
        acc[kf] = __builtin_amdgcn_mfma_f32_16x16x32_bf16(ah, qh[ds], acc[kf], 0, 0, 0);
        acc[kf] = __builtin_amdgcn_mfma_f32_16x16x32_bf16(ah, ql[ds], acc[kf], 0, 0, 0);
        acc[kf] = __builtin_amdgcn_mfma_f32_16x16x32_bf16(al, qh[ds], acc[kf], 0, 0, 0);
      }
    if (kt == qb0) {                        // diagonal tile: causal mask
#pragma unroll
      for (int kf = 0; kf < 4; ++kf)
#pragma unroll
        for (int r = 0; r < 4; ++r)
          if (kt + kf * 16 + lg * 4 + r > qrow) acc[kf][r] = -1e30f;
    }
    float tmax = -1e30f;
#pragma unroll
    for (int kf = 0; kf < 4; ++kf)
#pragma unroll
      for (int r = 0; r < 4; ++r) tmax = fmaxf(tmax, acc[kf][r]);
    tmax = fmaxf(tmax, __shfl_xor(tmax, 16));
    tmax = fmaxf(tmax, __shfl_xor(tmax, 32));
    float mnew = fmaxf(m, tmax);
    float ts = 0.0f;
#pragma unroll
    for (int kf = 0; kf < 4; ++kf)
#pragma unroll
      for (int r = 0; r < 4; ++r) ts += __expf(acc[kf][r] - mnew);
    ts += __shfl_xor(ts, 16);
    ts += __shfl_xor(ts, 32);
    l = l * __expf(m - mnew) + ts;
    m = mnew;
  }

  const float rl = 1.0f / l;
  f32x4 accO[8] = {};

  // ================= PASS 2: p -> cur (fp32) + pT (bf16) + PV =================
  for (int tile = 0; tile < ntiles; ++tile) {
    const int kt = tile * 64;
    __syncthreads();
#pragma unroll
    for (int r = 0; r < 4; ++r) {          // stage K hi/lo
      int cid = r * 256 + t;
      int k = cid >> 4, cp = cid & 15, c = cp ^ (k & 7);
      size_t goff = ((size_t)(kt + k) * NKVH + kh) * HDIM + c * 8;
      gload16(khi + goff, &Khi_s[cid * 8]);
      gload16(klo + goff, &Klo_s[cid * 8]);
    }
#pragma unroll
    for (int r = 0; r < 4; ++r) {          // stage V^T
      int cid = r * 256 + t;
      int d = cid >> 3, cp = cid & 7, c = cp ^ (d & 7);
      gload16(vt + ((size_t)kh * HDIM + d) * SEQ + kt + c * 8, &VT_s[cid * 8]);
    }
    __syncthreads();
    f32x4 acc[4] = {};
#pragma unroll
    for (int ds = 0; ds < 4; ++ds)
#pragma unroll
      for (int kf = 0; kf < 4; ++kf) {
        int krow = kf * 16 + lq;
        int cp = (ds * 4 + lg) ^ (krow & 7);
        bf16x8 ah = *(const bf16x8*)&Khi_s[krow * 128 + cp * 8];
        bf16x8 al = *(const bf16x8*)&Klo_s[krow * 128 + cp * 8];
        acc[kf] = __builtin_amdgcn_mfma_f32_16x16x32_bf16(ah, qh[ds], acc[kf], 0, 0, 0);
        acc[kf] = __builtin_amdgcn_mfma_f32_16x16x32_bf16(ah, ql[ds], acc[kf], 0, 0, 0);
        acc[kf] = __builtin_amdgcn_mfma_f32_16x16x32_bf16(al, qh[ds], acc[kf], 0, 0, 0);
      }
    if (kt == qb0) {
#pragma unroll
      for (int kf = 0; kf < 4; ++kf)
#pragma unroll
        for (int r = 0; r < 4; ++r)
          if (kt + kf * 16 + lg * 4 + r > qrow) acc[kf][r] = -1e30f;
    }
    // p = exp(s - m) / l ; write pT (bf16); cur from fp32 p
#pragma unroll
    for (int kf = 0; kf < 4; ++kf)
#pragma unroll
      for (int r = 0; r < 4; ++r) {
        float p = __expf(acc[kf][r] - m) * rl;
        acc[kf][r] = p;
        pT_s[wid][kf * 16 + lg * 4 + r][lq] = f2bf(p);
      }
#pragma unroll
    for (int kf = 0; kf < 4; ++kf)
#pragma unroll
      for (int r = 0; r < 4; ++r) {
        float v = acc[kf][r];
        v += __shfl_xor(v, 1); v += __shfl_xor(v, 2);
        v += __shfl_xor(v, 4); v += __shfl_xor(v, 8);
        acc[kf][r] = v;                    // q-sum for key kf*16+lg*4+r
      }
    {
      float sel = acc[0][0];
#pragma unroll
      for (int i = 1; i < 16; ++i) {
        float v = acc[i >> 2][i & 3];
        sel = (lq == i) ? v : sel;
      }
      int ksel = (lq >> 2) * 16 + lg * 4 + (lq & 3);   // 64 distinct keys per wave
      atomicAdd(&cur_scores[(size_t)h * SEQ + kt + ksel], sel);
    }
    __syncthreads();                       // pT visible to PV reads
#pragma unroll
    for (int ks = 0; ks < 2; ++ks) {
      const ushortT* pp = &pT_s[wid][ks * 32 + lg * 8][lq];
      bf16x8 pb;
#pragma unroll
      for (int j = 0; j < 8; ++j) pb[j] = (short)pp[j * 18];
#pragma unroll
      for (int fa = 0; fa < 8; ++fa) {
        int drow = fa * 16 + lq;
        int cp = (ks * 4 + lg) ^ (drow & 7);
        bf16x8 av = *(const bf16x8*)&VT_s[drow * 64 + cp * 8];
        accO[fa] = __builtin_amdgcn_mfma_f32_16x16x32_bf16(av, pb, accO[fa], 0, 0, 0);
      }
    }
  }

  // epilogue: O^T frag -> aout bf16 [S][NH*128]
#pragma unroll
  for (int fa = 0; fa < 8; ++fa) {
    ushort4 w4;
    w4.x = f2bf(accO[fa][0]); w4.y = f2bf(accO[fa][1]);
    w4.z = f2bf(accO[fa][2]); w4.w = f2bf(accO[fa][3]);
    *(ushort4*)(aout_bf + (size_t)qrow * (NHEAD * HDIM) + h * HDIM + fa * 16 + lg * 4) = w4;
  }
}

// ---------------- heavy-hitter top-k -> mask row ----------------
__global__ __launch_bounds__(256) void topk_mask_k(const float* __restrict__ cur,
                                                   float* __restrict__ maskout) {
  const int hh = blockIdx.x;
  const int t = threadIdx.x;
  __shared__ float vals[SELN];
  __shared__ float wv[4];
  __shared__ int   wi[4];
  for (int ccol = t; ccol < MCOLS; ccol += 256)
    maskout[(size_t)hh * MCOLS + ccol] = (ccol >= MCOLS - RECENT) ? 1.0f : 0.0f;
  for (int i = t; i < SELN; i += 256) vals[i] = cur[(size_t)hh * SEQ + i];
  __syncthreads();
  for (int it = 0; it < HEAVY; ++it) {
    float bv = -INFINITY; int bi = 0x7fffffff;
    for (int i = t; i < SELN; i += 256) {
      float v = vals[i];
      if (v > bv) { bv = v; bi = i; }
    }
    for (int off = 1; off < 64; off <<= 1) {
      float ov = __shfl_xor(bv, off); int oi = __shfl_xor(bi, off);
      if (ov > bv || (ov == bv && oi < bi)) { bv = ov; bi = oi; }
    }
    int w = t >> 6;
    if ((t & 63) == 0) { wv[w] = bv; wi[w] = bi; }
    __syncthreads();
    if (t == 0) {
      float fbv = wv[0]; int fbi = wi[0];
      for (int k = 1; k < 4; ++k)
        if (wv[k] > fbv || (wv[k] == fbv && wi[k] < fbi)) { fbv = wv[k]; fbi = wi[k]; }
      maskout[(size_t)hh * MCOLS + fbi] = 1.0f;
      vals[fbi] = -INFINITY;
    }
    __syncthreads();
  }
}

extern "C" void kernel_launch(void* const* d_in, const int* in_sizes, int n_in,
                              void* d_out, int out_size, void* d_ws, size_t ws_size,
                              hipStream_t stream) {
  const float* hs = (const float*)d_in[0];
  const float* Wq = (const float*)d_in[1];
  const float* bq = (const float*)d_in[2];
  const float* Wk = (const float*)d_in[3];
  const float* bk = (const float*)d_in[4];
  const float* Wv = (const float*)d_in[5];
  const float* bv = (const float*)d_in[6];
  const float* Wo = (const float*)d_in[7];
  float* out = (float*)d_out;
  float* maskout = out + (size_t)SEQ * HID;

  char* w = (char*)d_ws;
  auto alloc = [&](size_t bytes) { char* p = w; w += (bytes + 255) & ~(size_t)255; return p; };
  float*   qbuf   = (float*)alloc((size_t)SEQ * NHEAD * HDIM * 4);
  float*   kbuf   = (float*)alloc((size_t)SEQ * NKVH * HDIM * 4);
  float*   vbuf   = (float*)alloc((size_t)SEQ * NKVH * HDIM * 4);
  float*   cost   = (float*)alloc((size_t)SEQ * HDIM * 4);
  float*   sint   = (float*)alloc((size_t)SEQ * HDIM * 4);
  float*   cur    = (float*)alloc((size_t)NHEAD * SEQ * 4);
  ushortT* hshi   = (ushortT*)alloc((size_t)SEQ * HID * 2);
  ushortT* hslo   = (ushortT*)alloc((size_t)SEQ * HID * 2);
  ushortT* wqhi   = (ushortT*)alloc((size_t)HID * HID * 2);
  ushortT* wqlo   = (ushortT*)alloc((size_t)HID * HID * 2);
  ushortT* wkhi   = (ushortT*)alloc((size_t)NKVH * HDIM * HID * 2);
  ushortT* wklo   = (ushortT*)alloc((size_t)NKVH * HDIM * HID * 2);
  ushortT* wvhi   = (ushortT*)alloc((size_t)NKVH * HDIM * HID * 2);
  ushortT* wohi   = (ushortT*)alloc((size_t)HID * HID * 2);
  ushortT* aouthi = (ushortT*)alloc((size_t)SEQ * HID * 2);
  ushortT* khi_g  = (ushortT*)alloc((size_t)SEQ * NKVH * HDIM * 2);
  ushortT* klo_g  = (ushortT*)alloc((size_t)SEQ * NKVH * HDIM * 2);
  ushortT* vt_g   = (ushortT*)alloc((size_t)NKVH * HDIM * SEQ * 2);

  hipLaunchKernelGGL(rope_tables_k, dim3(SEQ), dim3(HDIM), 0, stream, cost, sint);

  {
    int n4;
    n4 = SEQ * HID / 4;
    hipLaunchKernelGGL(convert_split_k, dim3((n4 + 255) / 256), dim3(256), 0, stream, hs, hshi, hslo, n4);
    n4 = HID * HID / 4;
    hipLaunchKernelGGL(convert_split_k, dim3((n4 + 255) / 256), dim3(256), 0, stream, Wq, wqhi, wqlo, n4);
    n4 = NKVH * HDIM * HID / 4;
    hipLaunchKernelGGL(convert_split_k, dim3((n4 + 255) / 256), dim3(256), 0, stream, Wk, wkhi, wklo, n4);
    hipLaunchKernelGGL(convert_hi_k, dim3((n4 + 255) / 256), dim3(256), 0, stream, Wv, wvhi, n4);
    n4 = HID * HID / 4;
    hipLaunchKernelGGL(convert_hi_k, dim3((n4 + 255) / 256), dim3(256), 0, stream, Wo, wohi, n4);
  }

  hipLaunchKernelGGL((gemm_mfma_nt<3>), dim3((NHEAD * HDIM) / 128, SEQ / 128), dim3(256), 0, stream,
                     hshi, hslo, wqhi, wqlo, bq, qbuf, SEQ, NHEAD * HDIM, HID);
  hipLaunchKernelGGL((gemm_mfma_nt<3>), dim3((NKVH * HDIM) / 128, SEQ / 128), dim3(256), 0, stream,
                     hshi, hslo, wkhi, wklo, bk, kbuf, SEQ, NKVH * HDIM, HID);
  hipLaunchKernelGGL((gemm_mfma_nt<1>), dim3((NKVH * HDIM) / 128, SEQ / 128), dim3(256), 0, stream,
                     hshi, (const ushortT*)nullptr, wvhi, (const ushortT*)nullptr, bv, vbuf,
                     SEQ, NKVH * HDIM, HID);

  hipLaunchKernelGGL(rope_apply_k, dim3(SEQ, NHEAD), dim3(HDIM), 0, stream, qbuf, cost, sint, NHEAD);
  hipLaunchKernelGGL(rope_apply_k, dim3(SEQ, NKVH), dim3(HDIM), 0, stream, kbuf, cost, sint, NKVH);

  {
    int n4 = SEQ * NKVH * HDIM / 4;
    hipLaunchKernelGGL(convert_khl_k, dim3((n4 + 255) / 256), dim3(256), 0, stream, kbuf, khi_g, klo_g, n4);
  }
  hipLaunchKernelGGL(transpose_v_k, dim3(NKVH * HDIM * (SEQ / 8) / 256), dim3(256), 0, stream, vbuf, vt_g);

  hipMemsetAsync(cur, 0, (size_t)NHEAD * SEQ * sizeof(float), stream);

  hipLaunchKernelGGL(attn_mfma_k, dim3(SEQ / 64, NHEAD), dim3(256), 0, stream,
                     qbuf, khi_g, klo_g, vt_g, aouthi, cur);

  hipLaunchKernelGGL((gemm_mfma_nt<1>), dim3(HID / 128, SEQ / 128), dim3(256), 0, stream,
                     aouthi, (const ushortT*)nullptr, wohi, (const ushortT*)nullptr,
                     (const float*)nullptr, out, SEQ, HID, HID);

  hipLaunchKernelGGL(topk_mask_k, dim3(NHEAD), dim3(256), 0, stream, cur, maskout);
}

// Round 4
// 1090.817 us; speedup vs baseline: 5.7035x; 1.1624x over previous
//
#include <hip/hip_runtime.h>
#include <hip/hip_bf16.h>
#include <cfloat>
#include <math.h>

#define SEQ    2048
#define HID    4096
#define NHEAD  32
#define NKVH   8
#define HDIM   128
#define QKVN   6144            /* fused projection width: 4096 Q + 1024 K + 1024 V */
#define HEAVY  204
#define RECENT 204
#define SELN   (SEQ - RECENT)   /* 1844 */
#define MCOLS  (SEQ + 1)        /* 2049 */

typedef unsigned short ushortT;
typedef unsigned int uintT;

using bf16x8 = __attribute__((ext_vector_type(8))) short;
using f32x4  = __attribute__((ext_vector_type(4))) float;

// ---------------- helpers ----------------
__device__ __forceinline__ ushortT f2bf(float x) {
  uintT u = __float_as_uint(x);
  uintT r = (u + 0x7fffu + ((u >> 16) & 1u)) >> 16;   // RNE
  return (ushortT)r;
}
__device__ __forceinline__ float bf2f(ushortT h) {
  return __uint_as_float((uintT)h << 16);
}
__device__ __forceinline__ void gload16(const void* g, void* l) {
  __builtin_amdgcn_global_load_lds((const __attribute__((address_space(1))) void*)g,
                                   (__attribute__((address_space(3))) void*)l, 16, 0, 0);
}

// ---------------- RoPE tables (match numpy fp32 pipeline) ----------------
__global__ void rope_tables_k(float* __restrict__ cost, float* __restrict__ sint) {
  int s = blockIdx.x, d = threadIdx.x;
  int f = d & 63;
  float powv = (float)pow(10000.0, (double)f / 64.0);
  float invf = 1.0f / powv;
  float ang  = (float)s * invf;
  cost[s * HDIM + d] = (float)cos((double)ang);
  sint[s * HDIM + d] = (float)sin((double)ang);
}

// ---------------- RoPE apply to Q region of fused buffer, in place ----------------
__global__ void rope_q_k(float* __restrict__ x, const float* __restrict__ cost,
                         const float* __restrict__ sint) {
  int s = blockIdx.x, h = blockIdx.y, d = threadIdx.x;
  float* row = x + (size_t)s * QKVN + h * HDIM;
  float v  = row[d];
  float vp = row[d ^ 64];
  __syncthreads();
  float rot = (d < 64) ? -vp : vp;
  row[d] = v * cost[s * HDIM + d] + rot * sint[s * HDIM + d];
}

// ---------------- RoPE-K + scale + hi/lo split (reads fused, writes khi/klo) --------
__global__ void rope_k_split_k(const float* __restrict__ fused, const float* __restrict__ cost,
                               const float* __restrict__ sint, ushortT* __restrict__ khi,
                               ushortT* __restrict__ klo) {
  int s = blockIdx.x, kh = blockIdx.y, d = threadIdx.x;
  const float* row = fused + (size_t)s * QKVN + 4096 + kh * HDIM;
  float v  = row[d];
  float vp = row[d ^ 64];
  float rot = (d < 64) ? -vp : vp;
  float r = (v * cost[s * HDIM + d] + rot * sint[s * HDIM + d]) * 0.08838834764831845f;
  ushortT hh = f2bf(r);
  size_t o = ((size_t)s * NKVH + kh) * HDIM + d;
  khi[o] = hh;
  klo[o] = f2bf(r - bf2f(hh));
}

// ---------------- fp32 -> bf16 hi/lo split conversion ----------------
__global__ void convert_split_k(const float* __restrict__ src, ushortT* __restrict__ hi,
                                ushortT* __restrict__ lo, int n4) {
  int i = blockIdx.x * blockDim.x + threadIdx.x;
  if (i >= n4) return;
  float4 v = ((const float4*)src)[i];
  ushort4 h, l;
  h.x = f2bf(v.x); l.x = f2bf(v.x - bf2f(h.x));
  h.y = f2bf(v.y); l.y = f2bf(v.y - bf2f(h.y));
  h.z = f2bf(v.z); l.z = f2bf(v.z - bf2f(h.z));
  h.w = f2bf(v.w); l.w = f2bf(v.w - bf2f(h.w));
  ((ushort4*)hi)[i] = h;
  ((ushort4*)lo)[i] = l;
}
__global__ void convert_hi_k(const float* __restrict__ src, ushortT* __restrict__ hi, int n4) {
  int i = blockIdx.x * blockDim.x + threadIdx.x;
  if (i >= n4) return;
  float4 v = ((const float4*)src)[i];
  ushort4 h;
  h.x = f2bf(v.x); h.y = f2bf(v.y); h.z = f2bf(v.z); h.w = f2bf(v.w);
  ((ushort4*)hi)[i] = h;
}
__global__ void fuse_bias_k(const float* __restrict__ bq, const float* __restrict__ bk,
                            const float* __restrict__ bv, float* __restrict__ bias) {
  int i = blockIdx.x * 256 + threadIdx.x;
  if (i < 4096) bias[i] = bq[i];
  else if (i < 5120) bias[i] = bk[i - 4096];
  else if (i < QKVN) bias[i] = bv[i - 5120];
}

// ---------------- V transpose: fused V region fp32 -> vt [NKVH][128][S] bf16 --------
__global__ __launch_bounds__(256) void transpose_v_k(const float* __restrict__ fused,
                                                     ushortT* __restrict__ vt) {
  int g = blockIdx.x * 256 + threadIdx.x;
  int d = g & 127;
  int rest = g >> 7;
  int sblk = rest & (SEQ / 8 - 1);
  int kh = rest >> 8;
  ushortT tmp[8];
#pragma unroll
  for (int i = 0; i < 8; ++i) {
    float v = fused[(size_t)(sblk * 8 + i) * QKVN + 5120 + kh * HDIM + d];
    tmp[i] = f2bf(v);
  }
  ushortT* o = vt + ((size_t)kh * HDIM + d) * SEQ + sblk * 8;
  *(ushort4*)o = *(ushort4*)tmp;
  *(ushort4*)(o + 4) = *(ushort4*)&tmp[4];
}

// ---------------- bf16 MFMA NT GEMM (split-precision capable, prefetch) ----------------
template<int NPROD>
__global__ __launch_bounds__(256, NPROD == 3 ? 3 : 4) void gemm_mfma_nt(
    const ushortT* __restrict__ Ahi, const ushortT* __restrict__ Alo,
    const ushortT* __restrict__ Bhi, const ushortT* __restrict__ Blo,
    const float* __restrict__ bias, float* __restrict__ C,
    int M, int N, int K) {
  constexpr int NB = (NPROD == 3) ? 2 : 1;
  __shared__ __align__(16) ushortT As[NB][128 * 32];
  __shared__ __align__(16) ushortT Bs[NB][128 * 32];
  const int t = threadIdx.x;
  const int lane = t & 63, wid = t >> 6;
  const int wm = wid >> 1, wn = wid & 1;
  const size_t bm = (size_t)blockIdx.y * 128, bn = (size_t)blockIdx.x * 128;
  f32x4 acc[4][4] = {};
  const int r0 = t >> 2, kc0 = (t & 3) * 8;

  auto stage = [&](int k0) {
    const ushortT* ga = Ahi + (bm + r0) * (size_t)K + k0 + kc0;
    gload16(ga, &As[0][r0 * 32 + kc0]);
    gload16(ga + (size_t)64 * K, &As[0][(r0 + 64) * 32 + kc0]);
    const ushortT* gb = Bhi + (bn + r0) * (size_t)K + k0 + kc0;
    gload16(gb, &Bs[0][r0 * 32 + kc0]);
    gload16(gb + (size_t)64 * K, &Bs[0][(r0 + 64) * 32 + kc0]);
    if constexpr (NPROD == 3) {
      const ushortT* ga2 = Alo + (bm + r0) * (size_t)K + k0 + kc0;
      gload16(ga2, &As[1][r0 * 32 + kc0]);
      gload16(ga2 + (size_t)64 * K, &As[1][(r0 + 64) * 32 + kc0]);
      const ushortT* gb2 = Blo + (bn + r0) * (size_t)K + k0 + kc0;
      gload16(gb2, &Bs[1][r0 * 32 + kc0]);
      gload16(gb2 + (size_t)64 * K, &Bs[1][(r0 + 64) * 32 + kc0]);
    }
  };

  stage(0);
  for (int k0 = 0; k0 < K; k0 += 32) {
    __syncthreads();                 // drain: tile k0 resident in LDS
    const int frow = lane & 15, fk = (lane >> 4) * 8;
    bf16x8 ah[4], bh[4], al[4], bl[4];
#pragma unroll
    for (int f = 0; f < 4; ++f) {
      ah[f] = *(const bf16x8*)&As[0][(wm * 64 + f * 16 + frow) * 32 + fk];
      bh[f] = *(const bf16x8*)&Bs[0][(wn * 64 + f * 16 + frow) * 32 + fk];
      if constexpr (NPROD == 3) {
        al[f] = *(const bf16x8*)&As[1][(wm * 64 + f * 16 + frow) * 32 + fk];
        bl[f] = *(const bf16x8*)&Bs[1][(wn * 64 + f * 16 + frow) * 32 + fk];
      }
    }
    __syncthreads();                 // all waves done reading LDS
    if (k0 + 32 < K) stage(k0 + 32); // prefetch overlaps MFMA below
#pragma unroll
    for (int fr = 0; fr < 4; ++fr)
#pragma unroll
      for (int fc = 0; fc < 4; ++fc) {
        acc[fr][fc] = __builtin_amdgcn_mfma_f32_16x16x32_bf16(ah[fr], bh[fc], acc[fr][fc], 0, 0, 0);
        if constexpr (NPROD == 3) {
          acc[fr][fc] = __builtin_amdgcn_mfma_f32_16x16x32_bf16(ah[fr], bl[fc], acc[fr][fc], 0, 0, 0);
          acc[fr][fc] = __builtin_amdgcn_mfma_f32_16x16x32_bf16(al[fr], bh[fc], acc[fr][fc], 0, 0, 0);
        }
      }
  }
  const int crow = (lane >> 4) * 4, ccol = lane & 15;
#pragma unroll
  for (int fr = 0; fr < 4; ++fr)
#pragma unroll
    for (int fc = 0; fc < 4; ++fc) {
      size_t col = bn + wn * 64 + fc * 16 + ccol;
      float badd = bias ? bias[col] : 0.0f;
#pragma unroll
      for (int i = 0; i < 4; ++i) {
        size_t row = bm + wm * 64 + fr * 16 + crow + i;
        C[row * (size_t)N + col] = acc[fr][fc][i] + badd;
      }
    }
}

// ---------------- MFMA flash attention, two-pass, swapped (S^T = K·Q) ----------------
// grid (SEQ/128, NHEAD), 512 thr = 8 waves; wave owns 16 q-columns (128 q / block).
// K pre-scaled by 1/sqrt(128) and split hi/lo (3-product fp32-grade scores).
__global__ __launch_bounds__(512, 4) void attn_mfma_k(
    const float* __restrict__ qb, const ushortT* __restrict__ khi,
    const ushortT* __restrict__ klo, const ushortT* __restrict__ vt,
    ushortT* __restrict__ aout_bf, float* __restrict__ cur_scores) {
  const int h = blockIdx.y, kh = h >> 2;
  const int qb0 = ((int)gridDim.x - 1 - (int)blockIdx.x) * 128;   // big work first
  const int t = threadIdx.x, lane = t & 63, wid = t >> 6;
  const int lq = lane & 15, lg = lane >> 4;
  const int qrow = qb0 + wid * 16 + lq;

  __shared__ __align__(16) ushortT Khi_s[64 * 128];   // chunk-swizzled: c' = c ^ (k&7)
  __shared__ __align__(16) ushortT Klo_s[64 * 128];
  __shared__ __align__(16) ushortT VT_s[128 * 64];    // c' = c ^ (d&7)
  __shared__ ushortT pT_s[8][64][18];                 // per-wave P^T [k][q]
  __shared__ float cur_part[SEQ];

  for (int i = t; i < SEQ; i += 512) cur_part[i] = 0.0f;

  // ---- Q fragments (hi/lo) in registers
  bf16x8 qh[4], ql[4];
#pragma unroll
  for (int ds = 0; ds < 4; ++ds) {
    const float* qp = qb + (size_t)qrow * QKVN + h * HDIM + ds * 32 + lg * 8;
    float4 a = *(const float4*)qp, b = *(const float4*)(qp + 4);
    float v[8] = {a.x, a.y, a.z, a.w, b.x, b.y, b.z, b.w};
#pragma unroll
    for (int j = 0; j < 8; ++j) {
      ushortT hh = f2bf(v[j]);
      qh[ds][j] = (short)hh;
      ql[ds][j] = (short)f2bf(v[j] - bf2f(hh));
    }
  }

  const int ntiles = qb0 / 64 + 2;
  float m = -1e30f, l = 0.0f;

  auto stage_K = [&](int kt) {
#pragma unroll
    for (int r = 0; r < 2; ++r) {
      int cid = r * 512 + t;
      int k = cid >> 4, cp = cid & 15, c = cp ^ (k & 7);
      size_t goff = ((size_t)(kt + k) * NKVH + kh) * HDIM + c * 8;
      gload16(khi + goff, &Khi_s[cid * 8]);
      gload16(klo + goff, &Klo_s[cid * 8]);
    }
  };
  auto stage_V = [&](int kt) {
#pragma unroll
    for (int r = 0; r < 2; ++r) {
      int cid = r * 512 + t;
      int d = cid >> 3, cp = cid & 7, c = cp ^ (d & 7);
      gload16(vt + ((size_t)kh * HDIM + d) * SEQ + kt + c * 8, &VT_s[cid * 8]);
    }
  };
  auto qkt = [&](f32x4 (&acc)[4]) {
#pragma unroll
    for (int ds = 0; ds < 4; ++ds)
#pragma unroll
      for (int kf = 0; kf < 4; ++kf) {
        int krow = kf * 16 + lq;
        int cp = (ds * 4 + lg) ^ (krow & 7);
        bf16x8 ah = *(const bf16x8*)&Khi_s[krow * 128 + cp * 8];
        bf16x8 al = *(const bf16x8*)&Klo_s[krow * 128 + cp * 8];
        acc[kf] = __builtin_amdgcn_mfma_f32_16x16x32_bf16(ah, qh[ds], acc[kf], 0, 0, 0);
        acc[kf] = __builtin_amdgcn_mfma_f32_16x16x32_bf16(ah, ql[ds], acc[kf], 0, 0, 0);
        acc[kf] = __builtin_amdgcn_mfma_f32_16x16x32_bf16(al, qh[ds], acc[kf], 0, 0, 0);
      }
  };

  // ================= PASS 1: row max + denominator =================
  stage_K(0);
  for (int tile = 0; tile < ntiles; ++tile) {
    const int kt = tile * 64;
    __syncthreads();                       // K(t) resident
    const bool active = (kt <= qb0 + wid * 16 + 15);
    f32x4 acc[4] = {};
    if (active) qkt(acc);
    __syncthreads();                       // all LDS reads done
    if (tile + 1 < ntiles) stage_K(kt + 64);   // overlaps softmax VALU
    if (active) {
      if (kt + 63 > qb0 + wid * 16) {      // diagonal: causal mask
#pragma unroll
        for (int kf = 0; kf < 4; ++kf)
#pragma unroll
          for (int r = 0; r < 4; ++r)
            if (kt + kf * 16 + lg * 4 + r > qrow) acc[kf][r] = -1e30f;
      }
      float tmax = -1e30f;
#pragma unroll
      for (int kf = 0; kf < 4; ++kf)
#pragma unroll
        for (int r = 0; r < 4; ++r) tmax = fmaxf(tmax, acc[kf][r]);
      tmax = fmaxf(tmax, __shfl_xor(tmax, 16));
      tmax = fmaxf(tmax, __shfl_xor(tmax, 32));
      float mnew = fmaxf(m, tmax);
      float ts = 0.0f;
#pragma unroll
      for (int kf = 0; kf < 4; ++kf)
#pragma unroll
        for (int r = 0; r < 4; ++r) ts += __expf(acc[kf][r] - mnew);
      ts += __shfl_xor(ts, 16);
      ts += __shfl_xor(ts, 32);
      l = l * __expf(m - mnew) + ts;
      m = mnew;
    }
  }

  const float rl = 1.0f / l;
  f32x4 accO[8] = {};

  // ================= PASS 2: p -> cur (fp32) + pT (bf16) + PV =================
  stage_K(0);
  for (int tile = 0; tile < ntiles; ++tile) {
    const int kt = tile * 64;
    __syncthreads();                       // K(t) resident
    const bool active = (kt <= qb0 + wid * 16 + 15);
    f32x4 acc[4] = {};
    if (active) qkt(acc);
    __syncthreads();                       // all K-reads done; PV(t-1) done with VT_s
    stage_V(kt);
    if (tile + 1 < ntiles) stage_K(kt + 64);   // both overlap softmax VALU
    if (active) {
      if (kt + 63 > qb0 + wid * 16) {
#pragma unroll
        for (int kf = 0; kf < 4; ++kf)
#pragma unroll
          for (int r = 0; r < 4; ++r)
            if (kt + kf * 16 + lg * 4 + r > qrow) acc[kf][r] = -1e30f;
      }
#pragma unroll
      for (int kf = 0; kf < 4; ++kf)
#pragma unroll
        for (int r = 0; r < 4; ++r) {
          float p = __expf(acc[kf][r] - m) * rl;
          acc[kf][r] = p;
          pT_s[wid][kf * 16 + lg * 4 + r][lq] = f2bf(p);
        }
#pragma unroll
      for (int kf = 0; kf < 4; ++kf)
#pragma unroll
        for (int r = 0; r < 4; ++r) {
          float v = acc[kf][r];
          v += __shfl_xor(v, 1); v += __shfl_xor(v, 2);
          v += __shfl_xor(v, 4); v += __shfl_xor(v, 8);
          acc[kf][r] = v;                  // q-sum for key kf*16+lg*4+r
        }
      {
        float sel = acc[0][0];
#pragma unroll
        for (int i = 1; i < 16; ++i) {
          float v = acc[i >> 2][i & 3];
          sel = (lq == i) ? v : sel;
        }
        int ksel = (lq >> 2) * 16 + lg * 4 + (lq & 3);   // 64 distinct keys per wave
        atomicAdd(&cur_part[kt + ksel], sel);
      }
    }
    __syncthreads();                       // pT visible; V(t) resident
    if (active) {
#pragma unroll
      for (int ks = 0; ks < 2; ++ks) {
        const ushortT* pp = &pT_s[wid][ks * 32 + lg * 8][lq];
        bf16x8 pb;
#pragma unroll
        for (int j = 0; j < 8; ++j) pb[j] = (short)pp[j * 18];
#pragma unroll
        for (int fa = 0; fa < 8; ++fa) {
          int drow = fa * 16 + lq;
          int cp = (ks * 4 + lg) ^ (drow & 7);
          bf16x8 av = *(const bf16x8*)&VT_s[drow * 64 + cp * 8];
          accO[fa] = __builtin_amdgcn_mfma_f32_16x16x32_bf16(av, pb, accO[fa], 0, 0, 0);
        }
      }
    }
  }

  // flush cur_part -> global (one atomic per key per block)
  __syncthreads();
  const int kmax = qb0 + 128;
  for (int i = t; i < kmax; i += 512)
    atomicAdd(&cur_scores[(size_t)h * SEQ + i], cur_part[i]);

  // epilogue: O^T frag -> aout bf16 [S][NH*128]
#pragma unroll
  for (int fa = 0; fa < 8; ++fa) {
    ushort4 w4;
    w4.x = f2bf(accO[fa][0]); w4.y = f2bf(accO[fa][1]);
    w4.z = f2bf(accO[fa][2]); w4.w = f2bf(accO[fa][3]);
    *(ushort4*)(aout_bf + (size_t)qrow * (NHEAD * HDIM) + h * HDIM + fa * 16 + lg * 4) = w4;
  }
}

// ---------------- heavy-hitter top-k -> mask row ----------------
__global__ __launch_bounds__(256) void topk_mask_k(const float* __restrict__ cur,
                                                   float* __restrict__ maskout) {
  const int hh = blockIdx.x;
  const int t = threadIdx.x;
  __shared__ float vals[SELN];
  __shared__ float wv[4];
  __shared__ int   wi[4];
  for (int ccol = t; ccol < MCOLS; ccol += 256)
    maskout[(size_t)hh * MCOLS + ccol] = (ccol >= MCOLS - RECENT) ? 1.0f : 0.0f;
  for (int i = t; i < SELN; i += 256) vals[i] = cur[(size_t)hh * SEQ + i];
  __syncthreads();
  for (int it = 0; it < HEAVY; ++it) {
    float bv = -INFINITY; int bi = 0x7fffffff;
    for (int i = t; i < SELN; i += 256) {
      float v = vals[i];
      if (v > bv) { bv = v; bi = i; }
    }
    for (int off = 1; off < 64; off <<= 1) {
      float ov = __shfl_xor(bv, off); int oi = __shfl_xor(bi, off);
      if (ov > bv || (ov == bv && oi < bi)) { bv = ov; bi = oi; }
    }
    int w = t >> 6;
    if ((t & 63) == 0) { wv[w] = bv; wi[w] = bi; }
    __syncthreads();
    if (t == 0) {
      float fbv = wv[0]; int fbi = wi[0];
      for (int k = 1; k < 4; ++k)
        if (wv[k] > fbv || (wv[k] == fbv && wi[k] < fbi)) { fbv = wv[k]; fbi = wi[k]; }
      maskout[(size_t)hh * MCOLS + fbi] = 1.0f;
      vals[fbi] = -INFINITY;
    }
    __syncthreads();
  }
}

extern "C" void kernel_launch(void* const* d_in, const int* in_sizes, int n_in,
                              void* d_out, int out_size, void* d_ws, size_t ws_size,
                              hipStream_t stream) {
  const float* hs = (const float*)d_in[0];
  const float* Wq = (const float*)d_in[1];
  const float* bq = (const float*)d_in[2];
  const float* Wk = (const float*)d_in[3];
  const float* bk = (const float*)d_in[4];
  const float* Wv = (const float*)d_in[5];
  const float* bv = (const float*)d_in[6];
  const float* Wo = (const float*)d_in[7];
  float* out = (float*)d_out;
  float* maskout = out + (size_t)SEQ * HID;

  char* w = (char*)d_ws;
  auto alloc = [&](size_t bytes) { char* p = w; w += (bytes + 255) & ~(size_t)255; return p; };
  float*   fused  = (float*)alloc((size_t)SEQ * QKVN * 4);        // QKV projections
  float*   cost   = (float*)alloc((size_t)SEQ * HDIM * 4);
  float*   sint   = (float*)alloc((size_t)SEQ * HDIM * 4);
  float*   cur    = (float*)alloc((size_t)NHEAD * SEQ * 4);
  float*   biasf  = (float*)alloc((size_t)QKVN * 4);
  ushortT* hshi   = (ushortT*)alloc((size_t)SEQ * HID * 2);
  ushortT* hslo   = (ushortT*)alloc((size_t)SEQ * HID * 2);
  ushortT* whi    = (ushortT*)alloc((size_t)QKVN * HID * 2);
  ushortT* wlo    = (ushortT*)alloc((size_t)QKVN * HID * 2);
  ushortT* wohi   = (ushortT*)alloc((size_t)HID * HID * 2);
  // aliases: consumed-before-written ordering makes these safe
  ushortT* aouthi = hshi;                                  // attn out (after GEMM read hshi)
  ushortT* khi_g  = hslo;                                  // 2048*1024 each
  ushortT* klo_g  = hslo + (size_t)SEQ * NKVH * HDIM;
  ushortT* vt_g   = hslo + (size_t)2 * SEQ * NKVH * HDIM;

  hipLaunchKernelGGL(rope_tables_k, dim3(SEQ), dim3(HDIM), 0, stream, cost, sint);

  {
    int n4;
    n4 = SEQ * HID / 4;
    hipLaunchKernelGGL(convert_split_k, dim3((n4 + 255) / 256), dim3(256), 0, stream, hs, hshi, hslo, n4);
    n4 = HID * HID / 4;                       // Wq -> rows [0,4096)
    hipLaunchKernelGGL(convert_split_k, dim3((n4 + 255) / 256), dim3(256), 0, stream, Wq, whi, wlo, n4);
    n4 = NKVH * HDIM * HID / 4;               // Wk -> rows [4096,5120)
    hipLaunchKernelGGL(convert_split_k, dim3((n4 + 255) / 256), dim3(256), 0, stream, Wk,
                       whi + (size_t)4096 * HID, wlo + (size_t)4096 * HID, n4);
    hipLaunchKernelGGL(convert_split_k, dim3((n4 + 255) / 256), dim3(256), 0, stream, Wv,
                       whi + (size_t)5120 * HID, wlo + (size_t)5120 * HID, n4);
    n4 = HID * HID / 4;
    hipLaunchKernelGGL(convert_hi_k, dim3((n4 + 255) / 256), dim3(256), 0, stream, Wo, wohi, n4);
    hipLaunchKernelGGL(fuse_bias_k, dim3(QKVN / 256), dim3(256), 0, stream, bq, bk, bv, biasf);
  }

  // fused QKV projection (split-bf16, 3-product)
  hipLaunchKernelGGL((gemm_mfma_nt<3>), dim3(QKVN / 128, SEQ / 128), dim3(256), 0, stream,
                     hshi, hslo, whi, wlo, biasf, fused, SEQ, QKVN, HID);

  hipLaunchKernelGGL(rope_q_k, dim3(SEQ, NHEAD), dim3(HDIM), 0, stream, fused, cost, sint);
  hipLaunchKernelGGL(rope_k_split_k, dim3(SEQ, NKVH), dim3(HDIM), 0, stream, fused, cost, sint,
                     khi_g, klo_g);
  hipLaunchKernelGGL(transpose_v_k, dim3(NKVH * HDIM * (SEQ / 8) / 256), dim3(256), 0, stream,
                     fused, vt_g);

  hipMemsetAsync(cur, 0, (size_t)NHEAD * SEQ * sizeof(float), stream);

  hipLaunchKernelGGL(attn_mfma_k, dim3(SEQ / 128, NHEAD), dim3(512), 0, stream,
                     fused, khi_g, klo_g, vt_g, aouthi, cur);

  hipLaunchKernelGGL((gemm_mfma_nt<1>), dim3(HID / 128, SEQ / 128), dim3(256), 0, stream,
                     aouthi, (const ushortT*)nullptr, wohi, (const ushortT*)nullptr,
                     (const float*)nullptr, out, SEQ, HID, HID);

  hipLaunchKernelGGL(topk_mask_k, dim3(NHEAD), dim3(256), 0, stream, cur, maskout);
}

// Round 5
// 928.037 us; speedup vs baseline: 6.7039x; 1.1754x over previous
//
#include <hip/hip_runtime.h>
#include <hip/hip_bf16.h>
#include <cfloat>
#include <math.h>

#define SEQ    2048
#define HID    4096
#define NHEAD  32
#define NKVH   8
#define HDIM   128
#define QKVN   6144            /* fused projection width: 4096 Q + 1024 K + 1024 V */
#define HEAVY  204
#define RECENT 204
#define SELN   (SEQ - RECENT)   /* 1844 */
#define MCOLS  (SEQ + 1)        /* 2049 */

typedef unsigned short ushortT;
typedef unsigned int uintT;

using bf16x8 = __attribute__((ext_vector_type(8))) short;
using f32x4  = __attribute__((ext_vector_type(4))) float;

// ---------------- helpers ----------------
__device__ __forceinline__ ushortT f2bf(float x) {
  uintT u = __float_as_uint(x);
  uintT r = (u + 0x7fffu + ((u >> 16) & 1u)) >> 16;   // RNE
  return (ushortT)r;
}
__device__ __forceinline__ float bf2f(ushortT h) {
  return __uint_as_float((uintT)h << 16);
}
__device__ __forceinline__ void gload16(const void* g, void* l) {
  __builtin_amdgcn_global_load_lds((const __attribute__((address_space(1))) void*)g,
                                   (__attribute__((address_space(3))) void*)l, 16, 0, 0);
}

// ---------------- RoPE tables (match numpy fp32 pipeline) ----------------
__global__ void rope_tables_k(float* __restrict__ cost, float* __restrict__ sint) {
  int s = blockIdx.x, d = threadIdx.x;
  int f = d & 63;
  float powv = (float)pow(10000.0, (double)f / 64.0);
  float invf = 1.0f / powv;
  float ang  = (float)s * invf;
  cost[s * HDIM + d] = (float)cos((double)ang);
  sint[s * HDIM + d] = (float)sin((double)ang);
}

// ---------------- RoPE apply to Q region of fused buffer, in place ----------------
__global__ void rope_q_k(float* __restrict__ x, const float* __restrict__ cost,
                         const float* __restrict__ sint) {
  int s = blockIdx.x, h = blockIdx.y, d = threadIdx.x;
  float* row = x + (size_t)s * QKVN + h * HDIM;
  float v  = row[d];
  float vp = row[d ^ 64];
  __syncthreads();
  float rot = (d < 64) ? -vp : vp;
  row[d] = v * cost[s * HDIM + d] + rot * sint[s * HDIM + d];
}

// ---------------- RoPE-K + scale + hi/lo split (reads fused, writes khi/klo) --------
__global__ void rope_k_split_k(const float* __restrict__ fused, const float* __restrict__ cost,
                               const float* __restrict__ sint, ushortT* __restrict__ khi,
                               ushortT* __restrict__ klo) {
  int s = blockIdx.x, kh = blockIdx.y, d = threadIdx.x;
  const float* row = fused + (size_t)s * QKVN + 4096 + kh * HDIM;
  float v  = row[d];
  float vp = row[d ^ 64];
  float rot = (d < 64) ? -vp : vp;
  float r = (v * cost[s * HDIM + d] + rot * sint[s * HDIM + d]) * 0.08838834764831845f;
  ushortT hh = f2bf(r);
  size_t o = ((size_t)s * NKVH + kh) * HDIM + d;
  khi[o] = hh;
  klo[o] = f2bf(r - bf2f(hh));
}

// ---------------- fp32 -> bf16 hi/lo split conversion ----------------
__global__ void convert_split_k(const float* __restrict__ src, ushortT* __restrict__ hi,
                                ushortT* __restrict__ lo, int n4) {
  int i = blockIdx.x * blockDim.x + threadIdx.x;
  if (i >= n4) return;
  float4 v = ((const float4*)src)[i];
  ushort4 h, l;
  h.x = f2bf(v.x); l.x = f2bf(v.x - bf2f(h.x));
  h.y = f2bf(v.y); l.y = f2bf(v.y - bf2f(h.y));
  h.z = f2bf(v.z); l.z = f2bf(v.z - bf2f(h.z));
  h.w = f2bf(v.w); l.w = f2bf(v.w - bf2f(h.w));
  ((ushort4*)hi)[i] = h;
  ((ushort4*)lo)[i] = l;
}
__global__ void convert_hi_k(const float* __restrict__ src, ushortT* __restrict__ hi, int n4) {
  int i = blockIdx.x * blockDim.x + threadIdx.x;
  if (i >= n4) return;
  float4 v = ((const float4*)src)[i];
  ushort4 h;
  h.x = f2bf(v.x); h.y = f2bf(v.y); h.z = f2bf(v.z); h.w = f2bf(v.w);
  ((ushort4*)hi)[i] = h;
}
__global__ void fuse_bias_k(const float* __restrict__ bq, const float* __restrict__ bk,
                            const float* __restrict__ bv, float* __restrict__ bias) {
  int i = blockIdx.x * 256 + threadIdx.x;
  if (i < 4096) bias[i] = bq[i];
  else if (i < 5120) bias[i] = bk[i - 4096];
  else if (i < QKVN) bias[i] = bv[i - 5120];
}

// ---------------- V transpose: fused V region fp32 -> vt [NKVH][128][S] bf16 --------
__global__ __launch_bounds__(256) void transpose_v_k(const float* __restrict__ fused,
                                                     ushortT* __restrict__ vt) {
  int g = blockIdx.x * 256 + threadIdx.x;
  int d = g & 127;
  int rest = g >> 7;
  int sblk = rest & (SEQ / 8 - 1);
  int kh = rest >> 8;
  ushortT tmp[8];
#pragma unroll
  for (int i = 0; i < 8; ++i) {
    float v = fused[(size_t)(sblk * 8 + i) * QKVN + 5120 + kh * HDIM + d];
    tmp[i] = f2bf(v);
  }
  ushortT* o = vt + ((size_t)kh * HDIM + d) * SEQ + sblk * 8;
  *(ushort4*)o = *(ushort4*)tmp;
  *(ushort4*)(o + 4) = *(ushort4*)&tmp[4];
}

// ---------------- bf16 MFMA NT GEMM (split-precision capable, prefetch) ----------------
template<int NPROD>
__global__ __launch_bounds__(256, NPROD == 3 ? 3 : 4) void gemm_mfma_nt(
    const ushortT* __restrict__ Ahi, const ushortT* __restrict__ Alo,
    const ushortT* __restrict__ Bhi, const ushortT* __restrict__ Blo,
    const float* __restrict__ bias, float* __restrict__ C,
    int M, int N, int K) {
  constexpr int NB = (NPROD == 3) ? 2 : 1;
  __shared__ __align__(16) ushortT As[NB][128 * 32];
  __shared__ __align__(16) ushortT Bs[NB][128 * 32];
  const int t = threadIdx.x;
  const int lane = t & 63, wid = t >> 6;
  const int wm = wid >> 1, wn = wid & 1;
  const size_t bm = (size_t)blockIdx.y * 128, bn = (size_t)blockIdx.x * 128;
  f32x4 acc[4][4] = {};
  const int r0 = t >> 2, kc0 = (t & 3) * 8;

  auto stage = [&](int k0) {
    const ushortT* ga = Ahi + (bm + r0) * (size_t)K + k0 + kc0;
    gload16(ga, &As[0][r0 * 32 + kc0]);
    gload16(ga + (size_t)64 * K, &As[0][(r0 + 64) * 32 + kc0]);
    const ushortT* gb = Bhi + (bn + r0) * (size_t)K + k0 + kc0;
    gload16(gb, &Bs[0][r0 * 32 + kc0]);
    gload16(gb + (size_t)64 * K, &Bs[0][(r0 + 64) * 32 + kc0]);
    if constexpr (NPROD == 3) {
      const ushortT* ga2 = Alo + (bm + r0) * (size_t)K + k0 + kc0;
      gload16(ga2, &As[1][r0 * 32 + kc0]);
      gload16(ga2 + (size_t)64 * K, &As[1][(r0 + 64) * 32 + kc0]);
      const ushortT* gb2 = Blo + (bn + r0) * (size_t)K + k0 + kc0;
      gload16(gb2, &Bs[1][r0 * 32 + kc0]);
      gload16(gb2 + (size_t)64 * K, &Bs[1][(r0 + 64) * 32 + kc0]);
    }
  };

  stage(0);
  for (int k0 = 0; k0 < K; k0 += 32) {
    __syncthreads();                 // drain: tile k0 resident in LDS
    const int frow = lane & 15, fk = (lane >> 4) * 8;
    bf16x8 ah[4], bh[4], al[4], bl[4];
#pragma unroll
    for (int f = 0; f < 4; ++f) {
      ah[f] = *(const bf16x8*)&As[0][(wm * 64 + f * 16 + frow) * 32 + fk];
      bh[f] = *(const bf16x8*)&Bs[0][(wn * 64 + f * 16 + frow) * 32 + fk];
      if constexpr (NPROD == 3) {
        al[f] = *(const bf16x8*)&As[1][(wm * 64 + f * 16 + frow) * 32 + fk];
        bl[f] = *(const bf16x8*)&Bs[1][(wn * 64 + f * 16 + frow) * 32 + fk];
      }
    }
    __syncthreads();                 // all waves done reading LDS
    if (k0 + 32 < K) stage(k0 + 32); // prefetch overlaps MFMA below
#pragma unroll
    for (int fr = 0; fr < 4; ++fr)
#pragma unroll
      for (int fc = 0; fc < 4; ++fc) {
        acc[fr][fc] = __builtin_amdgcn_mfma_f32_16x16x32_bf16(ah[fr], bh[fc], acc[fr][fc], 0, 0, 0);
        if constexpr (NPROD == 3) {
          acc[fr][fc] = __builtin_amdgcn_mfma_f32_16x16x32_bf16(ah[fr], bl[fc], acc[fr][fc], 0, 0, 0);
          acc[fr][fc] = __builtin_amdgcn_mfma_f32_16x16x32_bf16(al[fr], bh[fc], acc[fr][fc], 0, 0, 0);
        }
      }
  }
  const int crow = (lane >> 4) * 4, ccol = lane & 15;
#pragma unroll
  for (int fr = 0; fr < 4; ++fr)
#pragma unroll
    for (int fc = 0; fc < 4; ++fc) {
      size_t col = bn + wn * 64 + fc * 16 + ccol;
      float badd = bias ? bias[col] : 0.0f;
#pragma unroll
      for (int i = 0; i < 4; ++i) {
        size_t row = bm + wm * 64 + fr * 16 + crow + i;
        C[row * (size_t)N + col] = acc[fr][fc][i] + badd;
      }
    }
}

// ---------------- MFMA flash attention, two-pass, swapped (S^T = K·Q) ----------------
// grid (SEQ/128, NHEAD), 256 thr = 4 waves; wave owns 32 q-columns (2 frags of 16).
// K pre-scaled by 1/sqrt(128) and split hi/lo (3-product fp32-grade scores).
// Each K/V fragment read from LDS feeds 2 q-fragments (6 MFMA per 2 reads).
__global__ __launch_bounds__(256, 2) void attn_mfma_k(
    const float* __restrict__ qb, const ushortT* __restrict__ khi,
    const ushortT* __restrict__ klo, const ushortT* __restrict__ vt,
    ushortT* __restrict__ aout_bf, float* __restrict__ cur_scores) {
  const int h = blockIdx.y, kh = h >> 2;
  const int qb0 = ((int)gridDim.x - 1 - (int)blockIdx.x) * 128;   // big work first
  const int t = threadIdx.x, lane = t & 63, wid = t >> 6;
  const int lq = lane & 15, lg = lane >> 4;

  __shared__ __align__(16) ushortT Khi_s[64 * 128];   // chunk-swizzled: c' = c ^ (k&7)
  __shared__ __align__(16) ushortT Klo_s[64 * 128];
  __shared__ __align__(16) ushortT VT_s[128 * 64];    // c' = c ^ (d&7)
  __shared__ __align__(16) ushortT p_s[4][32][72];    // per-wave P [q][k], pad 72
  __shared__ float cur_part[SEQ];

  for (int i = t; i < SEQ; i += 256) cur_part[i] = 0.0f;

  // ---- Q fragments (hi/lo) in registers; 2 q-frags of 16 columns each
  bf16x8 qh[2][4], ql[2][4];
#pragma unroll
  for (int qf = 0; qf < 2; ++qf) {
    const int qrow = qb0 + wid * 32 + qf * 16 + lq;
#pragma unroll
    for (int ds = 0; ds < 4; ++ds) {
      const float* qp = qb + (size_t)qrow * QKVN + h * HDIM + ds * 32 + lg * 8;
      float4 a = *(const float4*)qp, b = *(const float4*)(qp + 4);
      float v[8] = {a.x, a.y, a.z, a.w, b.x, b.y, b.z, b.w};
#pragma unroll
      for (int j = 0; j < 8; ++j) {
        ushortT hh = f2bf(v[j]);
        qh[qf][ds][j] = (short)hh;
        ql[qf][ds][j] = (short)f2bf(v[j] - bf2f(hh));
      }
    }
  }

  const int ntiles = qb0 / 64 + 2;
  const int qmaxw = qb0 + wid * 32 + 31;              // wave's largest q-row
  float m[2] = {-1e30f, -1e30f}, l[2] = {0.0f, 0.0f};

  auto stage_K = [&](int kt) {
#pragma unroll
    for (int r = 0; r < 4; ++r) {
      int cid = r * 256 + t;
      int k = cid >> 4, cp = cid & 15, c = cp ^ (k & 7);
      size_t goff = ((size_t)(kt + k) * NKVH + kh) * HDIM + c * 8;
      gload16(khi + goff, &Khi_s[cid * 8]);
      gload16(klo + goff, &Klo_s[cid * 8]);
    }
  };
  auto stage_V = [&](int kt) {
#pragma unroll
    for (int r = 0; r < 4; ++r) {
      int cid = r * 256 + t;
      int d = cid >> 3, cp = cid & 7, c = cp ^ (d & 7);
      gload16(vt + ((size_t)kh * HDIM + d) * SEQ + kt + c * 8, &VT_s[cid * 8]);
    }
  };
  auto qkt = [&](f32x4 (&acc)[4][2]) {
#pragma unroll
    for (int ds = 0; ds < 4; ++ds)
#pragma unroll
      for (int kf = 0; kf < 4; ++kf) {
        int krow = kf * 16 + lq;
        int cp = (ds * 4 + lg) ^ (krow & 7);
        bf16x8 ah = *(const bf16x8*)&Khi_s[krow * 128 + cp * 8];
        bf16x8 al = *(const bf16x8*)&Klo_s[krow * 128 + cp * 8];
#pragma unroll
        for (int qf = 0; qf < 2; ++qf) {
          acc[kf][qf] = __builtin_amdgcn_mfma_f32_16x16x32_bf16(ah, qh[qf][ds], acc[kf][qf], 0, 0, 0);
          acc[kf][qf] = __builtin_amdgcn_mfma_f32_16x16x32_bf16(ah, ql[qf][ds], acc[kf][qf], 0, 0, 0);
          acc[kf][qf] = __builtin_amdgcn_mfma_f32_16x16x32_bf16(al, qh[qf][ds], acc[kf][qf], 0, 0, 0);
        }
      }
  };

  // ================= PASS 1: row max + denominator =================
  stage_K(0);
  for (int tile = 0; tile < ntiles; ++tile) {
    const int kt = tile * 64;
    __syncthreads();                       // K(t) resident
    const bool active = (kt <= qmaxw);
    f32x4 acc[4][2] = {};
    if (active) qkt(acc);
    __syncthreads();                       // all LDS reads done
    if (tile + 1 < ntiles) stage_K(kt + 64);   // overlaps softmax VALU
    if (active) {
      const bool diag = (kt + 63 > qb0 + wid * 32);
#pragma unroll
      for (int qf = 0; qf < 2; ++qf) {
        const int qrow = qb0 + wid * 32 + qf * 16 + lq;
        if (diag) {
#pragma unroll
          for (int kf = 0; kf < 4; ++kf)
#pragma unroll
            for (int r = 0; r < 4; ++r)
              if (kt + kf * 16 + lg * 4 + r > qrow) acc[kf][qf][r] = -1e30f;
        }
        float tmax = -1e30f;
#pragma unroll
        for (int kf = 0; kf < 4; ++kf)
#pragma unroll
          for (int r = 0; r < 4; ++r) tmax = fmaxf(tmax, acc[kf][qf][r]);
        tmax = fmaxf(tmax, __shfl_xor(tmax, 16));
        tmax = fmaxf(tmax, __shfl_xor(tmax, 32));
        float mnew = fmaxf(m[qf], tmax);
        float ts = 0.0f;
#pragma unroll
        for (int kf = 0; kf < 4; ++kf)
#pragma unroll
          for (int r = 0; r < 4; ++r) ts += __expf(acc[kf][qf][r] - mnew);
        ts += __shfl_xor(ts, 16);
        ts += __shfl_xor(ts, 32);
        l[qf] = l[qf] * __expf(m[qf] - mnew) + ts;
        m[qf] = mnew;
      }
    }
  }

  const float rl0 = 1.0f / l[0], rl1 = 1.0f / l[1];
  f32x4 accO[8][2] = {};

  // ================= PASS 2: p -> cur (fp32) + p_s (bf16) + PV =================
  stage_K(0);
  for (int tile = 0; tile < ntiles; ++tile) {
    const int kt = tile * 64;
    __syncthreads();                       // K(t) resident; PV(t-1) done with VT_s
    stage_V(kt);                           // V(t) flies under QK^T + softmax
    const bool active = (kt <= qmaxw);
    f32x4 acc[4][2] = {};
    if (active) qkt(acc);
    __syncthreads();                       // all K-reads done
    if (tile + 1 < ntiles) stage_K(kt + 64);   // overlaps softmax VALU
    if (active) {
      const bool diag = (kt + 63 > qb0 + wid * 32);
      f32x4 csum[4];                       // per-key q-sums (over both qfrags)
#pragma unroll
      for (int kf = 0; kf < 4; ++kf)
#pragma unroll
        for (int r = 0; r < 4; ++r) csum[kf][r] = 0.0f;
#pragma unroll
      for (int qf = 0; qf < 2; ++qf) {
        const int qrow = qb0 + wid * 32 + qf * 16 + lq;
        const float rl = (qf == 0) ? rl0 : rl1;
        const float mq = m[qf];
        if (diag) {
#pragma unroll
          for (int kf = 0; kf < 4; ++kf)
#pragma unroll
            for (int r = 0; r < 4; ++r)
              if (kt + kf * 16 + lg * 4 + r > qrow) acc[kf][qf][r] = -1e30f;
        }
#pragma unroll
        for (int kf = 0; kf < 4; ++kf) {
          ushortT pk[4];
#pragma unroll
          for (int r = 0; r < 4; ++r) {
            float p = __expf(acc[kf][qf][r] - mq) * rl;
            csum[kf][r] += p;
            pk[r] = f2bf(p);
          }
          *(ushort4*)&p_s[wid][qf * 16 + lq][kf * 16 + lg * 4] = *(ushort4*)pk;
        }
      }
#pragma unroll
      for (int kf = 0; kf < 4; ++kf)
#pragma unroll
        for (int r = 0; r < 4; ++r) {
          float v = csum[kf][r];
          v += __shfl_xor(v, 1); v += __shfl_xor(v, 2);
          v += __shfl_xor(v, 4); v += __shfl_xor(v, 8);
          csum[kf][r] = v;                 // q-sum for key kf*16+lg*4+r
        }
      {
        float sel = csum[0][0];
#pragma unroll
        for (int i = 1; i < 16; ++i) {
          float v = csum[i >> 2][i & 3];
          sel = (lq == i) ? v : sel;
        }
        int ksel = (lq >> 2) * 16 + lg * 4 + (lq & 3);   // 64 distinct keys per wave
        atomicAdd(&cur_part[kt + ksel], sel);
      }
    }
    __syncthreads();                       // p_s visible; V(t) resident
    if (active) {
#pragma unroll
      for (int ks = 0; ks < 2; ++ks) {
        bf16x8 pb[2];
#pragma unroll
        for (int qf = 0; qf < 2; ++qf)
          pb[qf] = *(const bf16x8*)&p_s[wid][qf * 16 + lq][ks * 32 + lg * 8];
#pragma unroll
        for (int fa = 0; fa < 8; ++fa) {
          int drow = fa * 16 + lq;
          int cp = (ks * 4 + lg) ^ (drow & 7);
          bf16x8 av = *(const bf16x8*)&VT_s[drow * 64 + cp * 8];
          accO[fa][0] = __builtin_amdgcn_mfma_f32_16x16x32_bf16(av, pb[0], accO[fa][0], 0, 0, 0);
          accO[fa][1] = __builtin_amdgcn_mfma_f32_16x16x32_bf16(av, pb[1], accO[fa][1], 0, 0, 0);
        }
      }
    }
  }

  // flush cur_part -> global (one atomic per key per block)
  __syncthreads();
  const int kmax = qb0 + 128;
  for (int i = t; i < kmax; i += 256)
    atomicAdd(&cur_scores[(size_t)h * SEQ + i], cur_part[i]);

  // epilogue: O^T frag -> aout bf16 [S][NH*128]
#pragma unroll
  for (int qf = 0; qf < 2; ++qf) {
    const int qrow = qb0 + wid * 32 + qf * 16 + lq;
#pragma unroll
    for (int fa = 0; fa < 8; ++fa) {
      ushort4 w4;
      w4.x = f2bf(accO[fa][qf][0]); w4.y = f2bf(accO[fa][qf][1]);
      w4.z = f2bf(accO[fa][qf][2]); w4.w = f2bf(accO[fa][qf][3]);
      *(ushort4*)(aout_bf + (size_t)qrow * (NHEAD * HDIM) + h * HDIM + fa * 16 + lg * 4) = w4;
    }
  }
}

// ---------------- heavy-hitter top-k -> mask row ----------------
__global__ __launch_bounds__(256) void topk_mask_k(const float* __restrict__ cur,
                                                   float* __restrict__ maskout) {
  const int hh = blockIdx.x;
  const int t = threadIdx.x;
  __shared__ float vals[SELN];
  __shared__ float wv[4];
  __shared__ int   wi[4];
  for (int ccol = t; ccol < MCOLS; ccol += 256)
    maskout[(size_t)hh * MCOLS + ccol] = (ccol >= MCOLS - RECENT) ? 1.0f : 0.0f;
  for (int i = t; i < SELN; i += 256) vals[i] = cur[(size_t)hh * SEQ + i];
  __syncthreads();
  for (int it = 0; it < HEAVY; ++it) {
    float bv = -INFINITY; int bi = 0x7fffffff;
    for (int i = t; i < SELN; i += 256) {
      float v = vals[i];
      if (v > bv) { bv = v; bi = i; }
    }
    for (int off = 1; off < 64; off <<= 1) {
      float ov = __shfl_xor(bv, off); int oi = __shfl_xor(bi, off);
      if (ov > bv || (ov == bv && oi < bi)) { bv = ov; bi = oi; }
    }
    int w = t >> 6;
    if ((t & 63) == 0) { wv[w] = bv; wi[w] = bi; }
    __syncthreads();
    if (t == 0) {
      float fbv = wv[0]; int fbi = wi[0];
      for (int k = 1; k < 4; ++k)
        if (wv[k] > fbv || (wv[k] == fbv && wi[k] < fbi)) { fbv = wv[k]; fbi = wi[k]; }
      maskout[(size_t)hh * MCOLS + fbi] = 1.0f;
      vals[fbi] = -INFINITY;
    }
    __syncthreads();
  }
}

extern "C" void kernel_launch(void* const* d_in, const int* in_sizes, int n_in,
                              void* d_out, int out_size, void* d_ws, size_t ws_size,
                              hipStream_t stream) {
  const float* hs = (const float*)d_in[0];
  const float* Wq = (const float*)d_in[1];
  const float* bq = (const float*)d_in[2];
  const float* Wk = (const float*)d_in[3];
  const float* bk = (const float*)d_in[4];
  const float* Wv = (const float*)d_in[5];
  const float* bv = (const float*)d_in[6];
  const float* Wo = (const float*)d_in[7];
  float* out = (float*)d_out;
  float* maskout = out + (size_t)SEQ * HID;

  char* w = (char*)d_ws;
  auto alloc = [&](size_t bytes) { char* p = w; w += (bytes + 255) & ~(size_t)255; return p; };
  float*   fused  = (float*)alloc((size_t)SEQ * QKVN * 4);        // QKV projections
  float*   cost   = (float*)alloc((size_t)SEQ * HDIM * 4);
  float*   sint   = (float*)alloc((size_t)SEQ * HDIM * 4);
  float*   cur    = (float*)alloc((size_t)NHEAD * SEQ * 4);
  float*   biasf  = (float*)alloc((size_t)QKVN * 4);
  ushortT* hshi   = (ushortT*)alloc((size_t)SEQ * HID * 2);
  ushortT* hslo   = (ushortT*)alloc((size_t)SEQ * HID * 2);
  ushortT* whi    = (ushortT*)alloc((size_t)QKVN * HID * 2);
  ushortT* wlo    = (ushortT*)alloc((size_t)QKVN * HID * 2);
  ushortT* wohi   = (ushortT*)alloc((size_t)HID * HID * 2);
  // aliases: consumed-before-written ordering makes these safe
  ushortT* aouthi = hshi;                                  // attn out (after GEMM read hshi)
  ushortT* khi_g  = hslo;                                  // 2048*1024 each
  ushortT* klo_g  = hslo + (size_t)SEQ * NKVH * HDIM;
  ushortT* vt_g   = hslo + (size_t)2 * SEQ * NKVH * HDIM;

  hipLaunchKernelGGL(rope_tables_k, dim3(SEQ), dim3(HDIM), 0, stream, cost, sint);

  {
    int n4;
    n4 = SEQ * HID / 4;
    hipLaunchKernelGGL(convert_split_k, dim3((n4 + 255) / 256), dim3(256), 0, stream, hs, hshi, hslo, n4);
    n4 = HID * HID / 4;                       // Wq -> rows [0,4096)
    hipLaunchKernelGGL(convert_split_k, dim3((n4 + 255) / 256), dim3(256), 0, stream, Wq, whi, wlo, n4);
    n4 = NKVH * HDIM * HID / 4;               // Wk -> rows [4096,5120)
    hipLaunchKernelGGL(convert_split_k, dim3((n4 + 255) / 256), dim3(256), 0, stream, Wk,
                       whi + (size_t)4096 * HID, wlo + (size_t)4096 * HID, n4);
    hipLaunchKernelGGL(convert_split_k, dim3((n4 + 255) / 256), dim3(256), 0, stream, Wv,
                       whi + (size_t)5120 * HID, wlo + (size_t)5120 * HID, n4);
    n4 = HID * HID / 4;
    hipLaunchKernelGGL(convert_hi_k, dim3((n4 + 255) / 256), dim3(256), 0, stream, Wo, wohi, n4);
    hipLaunchKernelGGL(fuse_bias_k, dim3(QKVN / 256), dim3(256), 0, stream, bq, bk, bv, biasf);
  }

  // fused QKV projection (split-bf16, 3-product)
  hipLaunchKernelGGL((gemm_mfma_nt<3>), dim3(QKVN / 128, SEQ / 128), dim3(256), 0, stream,
                     hshi, hslo, whi, wlo, biasf, fused, SEQ, QKVN, HID);

  hipLaunchKernelGGL(rope_q_k, dim3(SEQ, NHEAD), dim3(HDIM), 0, stream, fused, cost, sint);
  hipLaunchKernelGGL(rope_k_split_k, dim3(SEQ, NKVH), dim3(HDIM), 0, stream, fused, cost, sint,
                     khi_g, klo_g);
  hipLaunchKernelGGL(transpose_v_k, dim3(NKVH * HDIM * (SEQ / 8) / 256), dim3(256), 0, stream,
                     fused, vt_g);

  hipMemsetAsync(cur, 0, (size_t)NHEAD * SEQ * sizeof(float), stream);

  hipLaunchKernelGGL(attn_mfma_k, dim3(SEQ / 128, NHEAD), dim3(256), 0, stream,
                     fused, khi_g, klo_g, vt_g, aouthi, cur);

  hipLaunchKernelGGL((gemm_mfma_nt<1>), dim3(HID / 128, SEQ / 128), dim3(256), 0, stream,
                     aouthi, (const ushortT*)nullptr, wohi, (const ushortT*)nullptr,
                     (const float*)nullptr, out, SEQ, HID, HID);

  hipLaunchKernelGGL(topk_mask_k, dim3(NHEAD), dim3(256), 0, stream, cur, maskout);
}

// Round 6
// 832.495 us; speedup vs baseline: 7.4732x; 1.1148x over previous
//
#include <hip/hip_runtime.h>
#include <hip/hip_bf16.h>
#include <cfloat>
#include <math.h>

#define SEQ    2048
#define HID    4096
#define NHEAD  32
#define NKVH   8
#define HDIM   128
#define QKVN   6144            /* fused projection width: 4096 Q + 1024 K + 1024 V */
#define HEAVY  204
#define RECENT 204
#define SELN   (SEQ - RECENT)   /* 1844 */
#define MCOLS  (SEQ + 1)        /* 2049 */

typedef unsigned short ushortT;
typedef unsigned int uintT;

using bf16x8 = __attribute__((ext_vector_type(8))) short;
using f32x4  = __attribute__((ext_vector_type(4))) float;

// ---------------- helpers ----------------
__device__ __forceinline__ ushortT f2bf(float x) {
  uintT u = __float_as_uint(x);
  uintT r = (u + 0x7fffu + ((u >> 16) & 1u)) >> 16;   // RNE
  return (ushortT)r;
}
__device__ __forceinline__ float bf2f(ushortT h) {
  return __uint_as_float((uintT)h << 16);
}
__device__ __forceinline__ void gload16(const void* g, void* l) {
  __builtin_amdgcn_global_load_lds((const __attribute__((address_space(1))) void*)g,
                                   (__attribute__((address_space(3))) void*)l, 16, 0, 0);
}

// ---------------- RoPE tables (match numpy fp32 pipeline) ----------------
__global__ void rope_tables_k(float* __restrict__ cost, float* __restrict__ sint) {
  int s = blockIdx.x, d = threadIdx.x;
  int f = d & 63;
  float powv = (float)pow(10000.0, (double)f / 64.0);
  float invf = 1.0f / powv;
  float ang  = (float)s * invf;
  cost[s * HDIM + d] = (float)cos((double)ang);
  sint[s * HDIM + d] = (float)sin((double)ang);
}

// ---------------- RoPE apply to Q region of fused buffer, in place ----------------
__global__ void rope_q_k(float* __restrict__ x, const float* __restrict__ cost,
                         const float* __restrict__ sint) {
  int s = blockIdx.x, h = blockIdx.y, d = threadIdx.x;
  float* row = x + (size_t)s * QKVN + h * HDIM;
  float v  = row[d];
  float vp = row[d ^ 64];
  __syncthreads();
  float rot = (d < 64) ? -vp : vp;
  row[d] = v * cost[s * HDIM + d] + rot * sint[s * HDIM + d];
}

// ---------------- RoPE-K + scale + hi/lo split (reads fused, writes khi/klo) --------
__global__ void rope_k_split_k(const float* __restrict__ fused, const float* __restrict__ cost,
                               const float* __restrict__ sint, ushortT* __restrict__ khi,
                               ushortT* __restrict__ klo) {
  int s = blockIdx.x, kh = blockIdx.y, d = threadIdx.x;
  const float* row = fused + (size_t)s * QKVN + 4096 + kh * HDIM;
  float v  = row[d];
  float vp = row[d ^ 64];
  float rot = (d < 64) ? -vp : vp;
  float r = (v * cost[s * HDIM + d] + rot * sint[s * HDIM + d]) * 0.08838834764831845f;
  ushortT hh = f2bf(r);
  size_t o = ((size_t)s * NKVH + kh) * HDIM + d;
  khi[o] = hh;
  klo[o] = f2bf(r - bf2f(hh));
}

// ---------------- fp32 -> bf16 hi/lo split conversion ----------------
__global__ void convert_split_k(const float* __restrict__ src, ushortT* __restrict__ hi,
                                ushortT* __restrict__ lo, int n4) {
  int i = blockIdx.x * blockDim.x + threadIdx.x;
  if (i >= n4) return;
  float4 v = ((const float4*)src)[i];
  ushort4 h, l;
  h.x = f2bf(v.x); l.x = f2bf(v.x - bf2f(h.x));
  h.y = f2bf(v.y); l.y = f2bf(v.y - bf2f(h.y));
  h.z = f2bf(v.z); l.z = f2bf(v.z - bf2f(h.z));
  h.w = f2bf(v.w); l.w = f2bf(v.w - bf2f(h.w));
  ((ushort4*)hi)[i] = h;
  ((ushort4*)lo)[i] = l;
}
// merged Wq|Wk|Wv split into fused layout rows [0,4096)|[4096,5120)|[5120,6144)
__global__ void convert_wqkv_k(const float* __restrict__ Wq, const float* __restrict__ Wk,
                               const float* __restrict__ Wv, ushortT* __restrict__ hi,
                               ushortT* __restrict__ lo) {
  int i = blockIdx.x * 256 + threadIdx.x;      // float4 index
  if (i >= QKVN * HID / 4) return;
  int e = i * 4;
  int row = e >> 12;
  const float* src;
  if (row < 4096)      src = Wq + e;
  else if (row < 5120) src = Wk + (e - (4096 << 12));
  else                 src = Wv + (e - (5120 << 12));
  float4 v = *(const float4*)src;
  ushort4 h, l;
  h.x = f2bf(v.x); l.x = f2bf(v.x - bf2f(h.x));
  h.y = f2bf(v.y); l.y = f2bf(v.y - bf2f(h.y));
  h.z = f2bf(v.z); l.z = f2bf(v.z - bf2f(h.z));
  h.w = f2bf(v.w); l.w = f2bf(v.w - bf2f(h.w));
  ((ushort4*)hi)[i] = h;
  ((ushort4*)lo)[i] = l;
}
__global__ void convert_hi_k(const float* __restrict__ src, ushortT* __restrict__ hi, int n4) {
  int i = blockIdx.x * blockDim.x + threadIdx.x;
  if (i >= n4) return;
  float4 v = ((const float4*)src)[i];
  ushort4 h;
  h.x = f2bf(v.x); h.y = f2bf(v.y); h.z = f2bf(v.z); h.w = f2bf(v.w);
  ((ushort4*)hi)[i] = h;
}
__global__ void fuse_bias_k(const float* __restrict__ bq, const float* __restrict__ bk,
                            const float* __restrict__ bv, float* __restrict__ bias) {
  int i = blockIdx.x * 256 + threadIdx.x;
  if (i < 4096) bias[i] = bq[i];
  else if (i < 5120) bias[i] = bk[i - 4096];
  else if (i < QKVN) bias[i] = bv[i - 5120];
}

// ---------------- V transpose: fused V region fp32 -> vt [NKVH][128][S] bf16 --------
__global__ __launch_bounds__(256) void transpose_v_k(const float* __restrict__ fused,
                                                     ushortT* __restrict__ vt) {
  int g = blockIdx.x * 256 + threadIdx.x;
  int d = g & 127;
  int rest = g >> 7;
  int sblk = rest & (SEQ / 8 - 1);
  int kh = rest >> 8;
  ushortT tmp[8];
#pragma unroll
  for (int i = 0; i < 8; ++i) {
    float v = fused[(size_t)(sblk * 8 + i) * QKVN + 5120 + kh * HDIM + d];
    tmp[i] = f2bf(v);
  }
  ushortT* o = vt + ((size_t)kh * HDIM + d) * SEQ + sblk * 8;
  *(ushort4*)o = *(ushort4*)tmp;
  *(ushort4*)(o + 4) = *(ushort4*)&tmp[4];
}

// ---------------- bf16 MFMA NT GEMM (split-precision, prefetch, XCD swizzle) --------
// 1D grid of nbx*nby blocks (must be %8==0); logical id XCD-chunked (T1/m204).
template<int NPROD>
__global__ __launch_bounds__(256, NPROD == 3 ? 3 : 4) void gemm_mfma_nt(
    const ushortT* __restrict__ Ahi, const ushortT* __restrict__ Alo,
    const ushortT* __restrict__ Bhi, const ushortT* __restrict__ Blo,
    const float* __restrict__ bias, float* __restrict__ C,
    int M, int N, int K, int nbx) {
  constexpr int NB = (NPROD == 3) ? 2 : 1;
  __shared__ __align__(16) ushortT As[NB][128 * 32];
  __shared__ __align__(16) ushortT Bs[NB][128 * 32];
  const int t = threadIdx.x;
  const int lane = t & 63, wid = t >> 6;
  const int wm = wid >> 1, wn = wid & 1;
  const int hw = blockIdx.x, cpx = (int)gridDim.x >> 3;
  const int lid = (hw & 7) * cpx + (hw >> 3);          // bijective: grid %8 == 0
  const size_t bm = (size_t)(lid / nbx) * 128, bn = (size_t)(lid % nbx) * 128;
  f32x4 acc[4][4] = {};
  const int r0 = t >> 2, kc0 = (t & 3) * 8;

  auto stage = [&](int k0) {
    const ushortT* ga = Ahi + (bm + r0) * (size_t)K + k0 + kc0;
    gload16(ga, &As[0][r0 * 32 + kc0]);
    gload16(ga + (size_t)64 * K, &As[0][(r0 + 64) * 32 + kc0]);
    const ushortT* gb = Bhi + (bn + r0) * (size_t)K + k0 + kc0;
    gload16(gb, &Bs[0][r0 * 32 + kc0]);
    gload16(gb + (size_t)64 * K, &Bs[0][(r0 + 64) * 32 + kc0]);
    if constexpr (NPROD == 3) {
      const ushortT* ga2 = Alo + (bm + r0) * (size_t)K + k0 + kc0;
      gload16(ga2, &As[1][r0 * 32 + kc0]);
      gload16(ga2 + (size_t)64 * K, &As[1][(r0 + 64) * 32 + kc0]);
      const ushortT* gb2 = Blo + (bn + r0) * (size_t)K + k0 + kc0;
      gload16(gb2, &Bs[1][r0 * 32 + kc0]);
      gload16(gb2 + (size_t)64 * K, &Bs[1][(r0 + 64) * 32 + kc0]);
    }
  };

  stage(0);
  for (int k0 = 0; k0 < K; k0 += 32) {
    __syncthreads();                 // drain: tile k0 resident in LDS
    const int frow = lane & 15, fk = (lane >> 4) * 8;
    bf16x8 ah[4], bh[4], al[4], bl[4];
#pragma unroll
    for (int f = 0; f < 4; ++f) {
      ah[f] = *(const bf16x8*)&As[0][(wm * 64 + f * 16 + frow) * 32 + fk];
      bh[f] = *(const bf16x8*)&Bs[0][(wn * 64 + f * 16 + frow) * 32 + fk];
      if constexpr (NPROD == 3) {
        al[f] = *(const bf16x8*)&As[1][(wm * 64 + f * 16 + frow) * 32 + fk];
        bl[f] = *(const bf16x8*)&Bs[1][(wn * 64 + f * 16 + frow) * 32 + fk];
      }
    }
    __syncthreads();                 // all waves done reading LDS
    if (k0 + 32 < K) stage(k0 + 32); // prefetch overlaps MFMA below
#pragma unroll
    for (int fr = 0; fr < 4; ++fr)
#pragma unroll
      for (int fc = 0; fc < 4; ++fc) {
        acc[fr][fc] = __builtin_amdgcn_mfma_f32_16x16x32_bf16(ah[fr], bh[fc], acc[fr][fc], 0, 0, 0);
        if constexpr (NPROD == 3) {
          acc[fr][fc] = __builtin_amdgcn_mfma_f32_16x16x32_bf16(ah[fr], bl[fc], acc[fr][fc], 0, 0, 0);
          acc[fr][fc] = __builtin_amdgcn_mfma_f32_16x16x32_bf16(al[fr], bh[fc], acc[fr][fc], 0, 0, 0);
        }
      }
  }
  const int crow = (lane >> 4) * 4, ccol = lane & 15;
#pragma unroll
  for (int fr = 0; fr < 4; ++fr)
#pragma unroll
    for (int fc = 0; fc < 4; ++fc) {
      size_t col = bn + wn * 64 + fc * 16 + ccol;
      float badd = bias ? bias[col] : 0.0f;
#pragma unroll
      for (int i = 0; i < 4; ++i) {
        size_t row = bm + wm * 64 + fr * 16 + crow + i;
        C[row * (size_t)N + col] = acc[fr][fc][i] + badd;
      }
    }
}

// ---------------- MFMA flash attention, two-pass, swapped (S^T = K·Q) ----------------
// 1D grid 512 (XCD-chunked: 4 heads per XCD), 256 thr = 4 waves; wave owns 32 q-cols.
// K pre-scaled by 1/sqrt(128) and split hi/lo (3-product fp32-grade scores).
__global__ __launch_bounds__(256, 2) void attn_mfma_k(
    const float* __restrict__ qb, const ushortT* __restrict__ khi,
    const ushortT* __restrict__ klo, const ushortT* __restrict__ vt,
    ushortT* __restrict__ aout_bf, float* __restrict__ cur_scores) {
  const int hw = blockIdx.x;
  const int lid = (hw & 7) * 64 + (hw >> 3);          // 512 % 8 == 0: bijective
  const int h = lid >> 4, kh = h >> 2;
  const int qb0 = (15 - (lid & 15)) * 128;            // big work first within head
  const int t = threadIdx.x, lane = t & 63, wid = t >> 6;
  const int lq = lane & 15, lg = lane >> 4;

  __shared__ __align__(16) ushortT Khi_s[64 * 128];   // chunk-swizzled: c' = c ^ (k&7)
  __shared__ __align__(16) ushortT Klo_s[64 * 128];
  __shared__ __align__(16) ushortT VT_s[128 * 64];    // c' = c ^ (d&7)
  __shared__ __align__(16) ushortT p_s[4][32][72];    // per-wave P [q][k], pad 72
  __shared__ float cur_part[SEQ];

  for (int i = t; i < SEQ; i += 256) cur_part[i] = 0.0f;

  // ---- Q fragments (hi/lo) in registers; 2 q-frags of 16 columns each
  bf16x8 qh[2][4], ql[2][4];
#pragma unroll
  for (int qf = 0; qf < 2; ++qf) {
    const int qrow = qb0 + wid * 32 + qf * 16 + lq;
#pragma unroll
    for (int ds = 0; ds < 4; ++ds) {
      const float* qp = qb + (size_t)qrow * QKVN + h * HDIM + ds * 32 + lg * 8;
      float4 a = *(const float4*)qp, b = *(const float4*)(qp + 4);
      float v[8] = {a.x, a.y, a.z, a.w, b.x, b.y, b.z, b.w};
#pragma unroll
      for (int j = 0; j < 8; ++j) {
        ushortT hh = f2bf(v[j]);
        qh[qf][ds][j] = (short)hh;
        ql[qf][ds][j] = (short)f2bf(v[j] - bf2f(hh));
      }
    }
  }

  const int ntiles = qb0 / 64 + 2;
  const int qmaxw = qb0 + wid * 32 + 31;              // wave's largest q-row
  float m[2] = {-1e30f, -1e30f}, l[2] = {0.0f, 0.0f};

  auto stage_K = [&](int kt) {
#pragma unroll
    for (int r = 0; r < 4; ++r) {
      int cid = r * 256 + t;
      int k = cid >> 4, cp = cid & 15, c = cp ^ (k & 7);
      size_t goff = ((size_t)(kt + k) * NKVH + kh) * HDIM + c * 8;
      gload16(khi + goff, &Khi_s[cid * 8]);
      gload16(klo + goff, &Klo_s[cid * 8]);
    }
  };
  auto stage_V = [&](int kt) {
#pragma unroll
    for (int r = 0; r < 4; ++r) {
      int cid = r * 256 + t;
      int d = cid >> 3, cp = cid & 7, c = cp ^ (d & 7);
      gload16(vt + ((size_t)kh * HDIM + d) * SEQ + kt + c * 8, &VT_s[cid * 8]);
    }
  };
  auto qkt = [&](f32x4 (&acc)[4][2]) {
#pragma unroll
    for (int ds = 0; ds < 4; ++ds)
#pragma unroll
      for (int kf = 0; kf < 4; ++kf) {
        int krow = kf * 16 + lq;
        int cp = (ds * 4 + lg) ^ (krow & 7);
        bf16x8 ah = *(const bf16x8*)&Khi_s[krow * 128 + cp * 8];
        bf16x8 al = *(const bf16x8*)&Klo_s[krow * 128 + cp * 8];
#pragma unroll
        for (int qf = 0; qf < 2; ++qf) {
          acc[kf][qf] = __builtin_amdgcn_mfma_f32_16x16x32_bf16(ah, qh[qf][ds], acc[kf][qf], 0, 0, 0);
          acc[kf][qf] = __builtin_amdgcn_mfma_f32_16x16x32_bf16(ah, ql[qf][ds], acc[kf][qf], 0, 0, 0);
          acc[kf][qf] = __builtin_amdgcn_mfma_f32_16x16x32_bf16(al, qh[qf][ds], acc[kf][qf], 0, 0, 0);
        }
      }
  };

  // ================= PASS 1: row max + denominator =================
  stage_K(0);
  for (int tile = 0; tile < ntiles; ++tile) {
    const int kt = tile * 64;
    __syncthreads();                       // K(t) resident
    const bool active = (kt <= qmaxw);
    f32x4 acc[4][2] = {};
    if (active) qkt(acc);
    __syncthreads();                       // all LDS reads done
    if (tile + 1 < ntiles) stage_K(kt + 64);   // overlaps softmax VALU
    if (active) {
      const bool diag = (kt + 63 > qb0 + wid * 32);
#pragma unroll
      for (int qf = 0; qf < 2; ++qf) {
        const int qrow = qb0 + wid * 32 + qf * 16 + lq;
        if (diag) {
#pragma unroll
          for (int kf = 0; kf < 4; ++kf)
#pragma unroll
            for (int r = 0; r < 4; ++r)
              if (kt + kf * 16 + lg * 4 + r > qrow) acc[kf][qf][r] = -1e30f;
        }
        float tmax = -1e30f;
#pragma unroll
        for (int kf = 0; kf < 4; ++kf)
#pragma unroll
          for (int r = 0; r < 4; ++r) tmax = fmaxf(tmax, acc[kf][qf][r]);
        tmax = fmaxf(tmax, __shfl_xor(tmax, 16));
        tmax = fmaxf(tmax, __shfl_xor(tmax, 32));
        float mnew = fmaxf(m[qf], tmax);
        float ts = 0.0f;
#pragma unroll
        for (int kf = 0; kf < 4; ++kf)
#pragma unroll
          for (int r = 0; r < 4; ++r) ts += __expf(acc[kf][qf][r] - mnew);
        ts += __shfl_xor(ts, 16);
        ts += __shfl_xor(ts, 32);
        l[qf] = l[qf] * __expf(m[qf] - mnew) + ts;
        m[qf] = mnew;
      }
    }
  }

  const float rl0 = 1.0f / l[0], rl1 = 1.0f / l[1];
  f32x4 accO[8][2] = {};

  // ================= PASS 2: p -> cur (fp32) + p_s (bf16) + PV =================
  stage_K(0);
  for (int tile = 0; tile < ntiles; ++tile) {
    const int kt = tile * 64;
    __syncthreads();                       // K(t) resident; PV(t-1) done with VT_s
    stage_V(kt);                           // V(t) flies under QK^T + softmax
    const bool active = (kt <= qmaxw);
    f32x4 acc[4][2] = {};
    if (active) qkt(acc);
    __syncthreads();                       // all K-reads done
    if (tile + 1 < ntiles) stage_K(kt + 64);   // overlaps softmax VALU
    if (active) {
      const bool diag = (kt + 63 > qb0 + wid * 32);
      f32x4 csum[4];                       // per-key q-sums (over both qfrags)
#pragma unroll
      for (int kf = 0; kf < 4; ++kf)
#pragma unroll
        for (int r = 0; r < 4; ++r) csum[kf][r] = 0.0f;
#pragma unroll
      for (int qf = 0; qf < 2; ++qf) {
        const int qrow = qb0 + wid * 32 + qf * 16 + lq;
        const float rl = (qf == 0) ? rl0 : rl1;
        const float mq = m[qf];
        if (diag) {
#pragma unroll
          for (int kf = 0; kf < 4; ++kf)
#pragma unroll
            for (int r = 0; r < 4; ++r)
              if (kt + kf * 16 + lg * 4 + r > qrow) acc[kf][qf][r] = -1e30f;
        }
#pragma unroll
        for (int kf = 0; kf < 4; ++kf) {
          ushortT pk[4];
#pragma unroll
          for (int r = 0; r < 4; ++r) {
            float p = __expf(acc[kf][qf][r] - mq) * rl;
            csum[kf][r] += p;
            pk[r] = f2bf(p);
          }
          *(ushort4*)&p_s[wid][qf * 16 + lq][kf * 16 + lg * 4] = *(ushort4*)pk;
        }
      }
#pragma unroll
      for (int kf = 0; kf < 4; ++kf)
#pragma unroll
        for (int r = 0; r < 4; ++r) {
          float v = csum[kf][r];
          v += __shfl_xor(v, 1); v += __shfl_xor(v, 2);
          v += __shfl_xor(v, 4); v += __shfl_xor(v, 8);
          csum[kf][r] = v;                 // q-sum for key kf*16+lg*4+r
        }
      {
        float sel = csum[0][0];
#pragma unroll
        for (int i = 1; i < 16; ++i) {
          float v = csum[i >> 2][i & 3];
          sel = (lq == i) ? v : sel;
        }
        int ksel = (lq >> 2) * 16 + lg * 4 + (lq & 3);   // 64 distinct keys per wave
        atomicAdd(&cur_part[kt + ksel], sel);
      }
    }
    __syncthreads();                       // p_s visible; V(t) resident
    if (active) {
#pragma unroll
      for (int ks = 0; ks < 2; ++ks) {
        bf16x8 pb[2];
#pragma unroll
        for (int qf = 0; qf < 2; ++qf)
          pb[qf] = *(const bf16x8*)&p_s[wid][qf * 16 + lq][ks * 32 + lg * 8];
#pragma unroll
        for (int fa = 0; fa < 8; ++fa) {
          int drow = fa * 16 + lq;
          int cp = (ks * 4 + lg) ^ (drow & 7);
          bf16x8 av = *(const bf16x8*)&VT_s[drow * 64 + cp * 8];
          accO[fa][0] = __builtin_amdgcn_mfma_f32_16x16x32_bf16(av, pb[0], accO[fa][0], 0, 0, 0);
          accO[fa][1] = __builtin_amdgcn_mfma_f32_16x16x32_bf16(av, pb[1], accO[fa][1], 0, 0, 0);
        }
      }
    }
  }

  // flush cur_part -> global (one atomic per key per block)
  __syncthreads();
  const int kmax = qb0 + 128;
  for (int i = t; i < kmax; i += 256)
    atomicAdd(&cur_scores[(size_t)h * SEQ + i], cur_part[i]);

  // epilogue: O^T frag -> aout bf16 [S][NH*128]
#pragma unroll
  for (int qf = 0; qf < 2; ++qf) {
    const int qrow = qb0 + wid * 32 + qf * 16 + lq;
#pragma unroll
    for (int fa = 0; fa < 8; ++fa) {
      ushort4 w4;
      w4.x = f2bf(accO[fa][qf][0]); w4.y = f2bf(accO[fa][qf][1]);
      w4.z = f2bf(accO[fa][qf][2]); w4.w = f2bf(accO[fa][qf][3]);
      *(ushort4*)(aout_bf + (size_t)qrow * (NHEAD * HDIM) + h * HDIM + fa * 16 + lg * 4) = w4;
    }
  }
}

// ---------------- heavy-hitter top-k via exact radix-select -> mask row ----------------
// cur values are sums of exp() terms: all >= 0, so uint bit order == float order.
// T = 204th largest; mark all > T, then fill == T in ascending index order
// (matches lax.top_k stable tie-break: higher value first, then lower index).
__global__ __launch_bounds__(256) void topk_mask_k(const float* __restrict__ cur,
                                                   float* __restrict__ maskout) {
  const int hh = blockIdx.x;
  const int t = threadIdx.x;
  __shared__ uintT vals[SELN];
  __shared__ uintT hist[256];
  __shared__ uintT sh_prefix, sh_k;
  float* mrow = maskout + (size_t)hh * MCOLS;
  for (int c = t; c < MCOLS; c += 256)
    mrow[c] = (c >= MCOLS - RECENT) ? 1.0f : 0.0f;
  for (int i = t; i < SELN; i += 256)
    vals[i] = __float_as_uint(cur[(size_t)hh * SEQ + i]);
  if (t == 0) { sh_prefix = 0u; sh_k = HEAVY; }
  __syncthreads();
#pragma unroll
  for (int shift = 24; shift >= 0; shift -= 8) {
    if (t < 256) hist[t] = 0;
    __syncthreads();
    const uintT pre = sh_prefix;
    const uintT maskhi = (shift == 24) ? 0u : (0xFFFFFFFFu << (shift + 8));
    for (int i = t; i < SELN; i += 256) {
      uintT v = vals[i];
      if ((v & maskhi) == pre) atomicAdd(&hist[(v >> shift) & 255u], 1u);
    }
    __syncthreads();
    if (t == 0) {
      uintT k = sh_k, cum = 0; int bsel = 0;
      for (int b = 255; b >= 0; --b) {
        if (cum + hist[b] >= k) { bsel = b; break; }
        cum += hist[b];
      }
      sh_prefix = pre | ((uintT)bsel << shift);
      sh_k = k - cum;                         // how many needed from == tier at this level
    }
    __syncthreads();
  }
  const uintT T = sh_prefix;                  // exact bits of 204th-largest value
  const uintT need = sh_k;                    // # of == T elements to include
  for (int i = t; i < SELN; i += 256)
    if (vals[i] > T) mrow[i] = 1.0f;
  __syncthreads();
  if (t == 0) {
    uintT taken = 0;
    for (int i = 0; i < SELN && taken < need; ++i)
      if (vals[i] == T) { mrow[i] = 1.0f; ++taken; }
  }
}

extern "C" void kernel_launch(void* const* d_in, const int* in_sizes, int n_in,
                              void* d_out, int out_size, void* d_ws, size_t ws_size,
                              hipStream_t stream) {
  const float* hs = (const float*)d_in[0];
  const float* Wq = (const float*)d_in[1];
  const float* bq = (const float*)d_in[2];
  const float* Wk = (const float*)d_in[3];
  const float* bk = (const float*)d_in[4];
  const float* Wv = (const float*)d_in[5];
  const float* bv = (const float*)d_in[6];
  const float* Wo = (const float*)d_in[7];
  float* out = (float*)d_out;
  float* maskout = out + (size_t)SEQ * HID;

  char* w = (char*)d_ws;
  auto alloc = [&](size_t bytes) { char* p = w; w += (bytes + 255) & ~(size_t)255; return p; };
  float*   fused  = (float*)alloc((size_t)SEQ * QKVN * 4);        // QKV projections
  float*   cost   = (float*)alloc((size_t)SEQ * HDIM * 4);
  float*   sint   = (float*)alloc((size_t)SEQ * HDIM * 4);
  float*   cur    = (float*)alloc((size_t)NHEAD * SEQ * 4);
  float*   biasf  = (float*)alloc((size_t)QKVN * 4);
  ushortT* hshi   = (ushortT*)alloc((size_t)SEQ * HID * 2);
  ushortT* hslo   = (ushortT*)alloc((size_t)SEQ * HID * 2);
  ushortT* whi    = (ushortT*)alloc((size_t)QKVN * HID * 2);
  ushortT* wlo    = (ushortT*)alloc((size_t)QKVN * HID * 2);
  ushortT* wohi   = (ushortT*)alloc((size_t)HID * HID * 2);
  // aliases: consumed-before-written ordering makes these safe
  ushortT* aouthi = hshi;                                  // attn out (after GEMM read hshi)
  ushortT* khi_g  = hslo;                                  // 2048*1024 each
  ushortT* klo_g  = hslo + (size_t)SEQ * NKVH * HDIM;
  ushortT* vt_g   = hslo + (size_t)2 * SEQ * NKVH * HDIM;

  hipLaunchKernelGGL(rope_tables_k, dim3(SEQ), dim3(HDIM), 0, stream, cost, sint);

  {
    int n4;
    n4 = SEQ * HID / 4;
    hipLaunchKernelGGL(convert_split_k, dim3((n4 + 255) / 256), dim3(256), 0, stream, hs, hshi, hslo, n4);
    n4 = QKVN * HID / 4;                      // Wq|Wk|Wv merged split
    hipLaunchKernelGGL(convert_wqkv_k, dim3((n4 + 255) / 256), dim3(256), 0, stream,
                       Wq, Wk, Wv, whi, wlo);
    n4 = HID * HID / 4;
    hipLaunchKernelGGL(convert_hi_k, dim3((n4 + 255) / 256), dim3(256), 0, stream, Wo, wohi, n4);
    hipLaunchKernelGGL(fuse_bias_k, dim3(QKVN / 256), dim3(256), 0, stream, bq, bk, bv, biasf);
  }

  // fused QKV projection (split-bf16, 3-product), 1D grid 768 (XCD-swizzled)
  hipLaunchKernelGGL((gemm_mfma_nt<3>), dim3((QKVN / 128) * (SEQ / 128)), dim3(256), 0, stream,
                     hshi, hslo, whi, wlo, biasf, fused, SEQ, QKVN, HID, QKVN / 128);

  hipLaunchKernelGGL(rope_q_k, dim3(SEQ, NHEAD), dim3(HDIM), 0, stream, fused, cost, sint);
  hipLaunchKernelGGL(rope_k_split_k, dim3(SEQ, NKVH), dim3(HDIM), 0, stream, fused, cost, sint,
                     khi_g, klo_g);
  hipLaunchKernelGGL(transpose_v_k, dim3(NKVH * HDIM * (SEQ / 8) / 256), dim3(256), 0, stream,
                     fused, vt_g);

  hipMemsetAsync(cur, 0, (size_t)NHEAD * SEQ * sizeof(float), stream);

  hipLaunchKernelGGL(attn_mfma_k, dim3((SEQ / 128) * NHEAD), dim3(256), 0, stream,
                     fused, khi_g, klo_g, vt_g, aouthi, cur);

  // out projection, 1D grid 512 (XCD-swizzled)
  hipLaunchKernelGGL((gemm_mfma_nt<1>), dim3((HID / 128) * (SEQ / 128)), dim3(256), 0, stream,
                     aouthi, (const ushortT*)nullptr, wohi, (const ushortT*)nullptr,
                     (const float*)nullptr, out, SEQ, HID, HID, HID / 128);

  hipLaunchKernelGGL(topk_mask_k, dim3(NHEAD), dim3(256), 0, stream, cur, maskout);
}